// Round 11
// baseline (170.529 us; speedup 1.0000x reference)
//
#include <hip/hip_runtime.h>
#include <math.h>

#define Ss 2048
#define Dd 1024
#define Pp 9
#define DMm 256
#define Tt 8192
#define EPSf 1e-5f
#define BAND 6e-3f       // fp64-rescue band for argmax ties

typedef __attribute__((ext_vector_type(8))) __bf16 bf16x8;
typedef __attribute__((ext_vector_type(4))) float f32x4;

#define GLOBAL_AS __attribute__((address_space(1)))
#define LDS_AS __attribute__((address_space(3)))

#define MAXTILES 137     // sum_p ceil(cnt_p/64) <= 8192/64 + 9

__device__ __forceinline__ unsigned short bf16rn(float f) {
  unsigned int u = __float_as_uint(f);
  unsigned int r = (u + 0x7fffu + ((u >> 16) & 1u)) >> 16;
  return (unsigned short)r;
}

__device__ __forceinline__ void gload16(const void* g, void* l) {
  __builtin_amdgcn_global_load_lds((const GLOBAL_AS unsigned int*)g,
                                   (LDS_AS unsigned int*)l, 16, 0, 0);
}

// swizzled LDS short-offset, BK=64 rows (8 x 16B slots/row)
#define KSW(r, sl) (((r) << 6) + ((((sl) ^ ((r) & 7))) << 3))

// ---------------------------------------------------------------- prep: mix -> bf16 + weight cvt/T + zero counts
__global__ __launch_bounds__(256) void k_prep(const float* __restrict__ x,
    const float* __restrict__ mk, unsigned short* __restrict__ xh,
    const float* __restrict__ W1, const float* __restrict__ W2,
    const float* __restrict__ Wo1,
    unsigned short* __restrict__ W1t, unsigned short* __restrict__ W2t,
    unsigned short* __restrict__ Wo1t, int* __restrict__ counts) {
  const int bid = blockIdx.x;
  if (bid < Tt) {
    if (bid == 0 && threadIdx.x < 64) counts[threadIdx.x] = 0;
    const int t = bid;
    const int s = t & (Ss - 1);
    const int d = threadIdx.x << 2;
    const float* xc = x + (size_t)t * Dd + d;
    float4 vb = *(const float4*)xc;
    float4 va = make_float4(0.f, 0.f, 0.f, 0.f);
    float4 vc = make_float4(0.f, 0.f, 0.f, 0.f);
    if (s > 0)      va = *(const float4*)(xc - Dd);
    if (s < Ss - 1) vc = *(const float4*)(xc + Dd);
    const float4 k0 = *(const float4*)(mk + d);
    const float4 k1 = *(const float4*)(mk + Dd + d);
    const float4 k2 = *(const float4*)(mk + 2 * Dd + d);
    float4 o;
    o.x = k0.x * va.x + k1.x * vb.x + k2.x * vc.x;
    o.y = k0.y * va.y + k1.y * vb.y + k2.y * vc.y;
    o.z = k0.z * va.z + k1.z * vb.z + k2.z * vc.z;
    o.w = k0.w * va.w + k1.w * vb.w + k2.w * vc.w;
    ushort4 h;
    h.x = bf16rn(o.x); h.y = bf16rn(o.y); h.z = bf16rn(o.z); h.w = bf16rn(o.w);
    *(ushort4*)(xh + (size_t)t * Dd + d) = h;
    return;
  }
  // weight convert+transpose: i in [0, 19*256)
  const int i = bid - Tt;
  const int z = i >> 8, rem = i & 255;
  const int bx = rem & 31, by = rem >> 5;
  const float* in; unsigned short* outp; int R, C, r0, c0;
  if (z < Pp)          { in = W1;  outp = W1t;  R = Dd;  C = DMm; r0 = bx * 32; c0 = by * 32; }
  else if (z < 2 * Pp) { in = W2;  outp = W2t;  R = DMm; C = Dd;  r0 = by * 32; c0 = bx * 32; }
  else                 { in = Wo1; outp = Wo1t; R = Dd;  C = DMm; r0 = bx * 32; c0 = by * 32; }
  const int zi = (z < Pp) ? z : ((z < 2 * Pp) ? z - Pp : 0);
  const size_t zo = (size_t)zi * R * C;
  __shared__ float tile[32][33];
  const int tr = threadIdx.x >> 3, tc = (threadIdx.x & 7) << 2;
  float4 v = *(const float4*)(in + zo + (size_t)(r0 + tr) * C + c0 + tc);
  tile[tr][tc] = v.x; tile[tr][tc + 1] = v.y; tile[tr][tc + 2] = v.z; tile[tr][tc + 3] = v.w;
  __syncthreads();
  ushort4 h;
  h.x = bf16rn(tile[tc + 0][tr]); h.y = bf16rn(tile[tc + 1][tr]);
  h.z = bf16rn(tile[tc + 2][tr]); h.w = bf16rn(tile[tc + 3][tr]);
  *(ushort4*)(outp + zo + (size_t)(c0 + tr) * R + r0 + tc) = h;
}

// ---------------------------------------------------------------- pipelined MFMA GEMM, 64x128 tile, BK=64 (R7 geometry)
// MODE 0: outf = tanh(acc+bias)   MODE 1: outh = bf16(acc+bias)   MODE 2: outf = acc+bias+resid
template<int KTOT, int NTOT, int MODE, bool GROUPED>
__global__ __launch_bounds__(256) void k_gemm(
    const unsigned short* __restrict__ A,
    const unsigned short* __restrict__ Bt,
    const float* __restrict__ bias,
    const float* __restrict__ resid,
    float* __restrict__ outf, unsigned short* __restrict__ outh,
    const int* __restrict__ counts, const int* __restrict__ tokenlist) {
  int p = 0, ti = blockIdx.x, cnt = Tt;
  if (GROUPED) {
    for (p = 0; p < Pp; ++p) {
      cnt = counts[p];
      const int nt = (cnt + 63) >> 6;
      if (ti < nt) break;
      ti -= nt;
    }
    if (p == Pp) return;
  }
  const int tile0 = ti * 64;
  __shared__ int tl[64];
  __shared__ __align__(16) unsigned short As[2][64 * 64];   // 2 x 8 KB
  __shared__ __align__(16) unsigned short Bs[2][128 * 64];  // 2 x 16 KB
  const int tid = threadIdx.x;
  if (tid < 64) {
    const int li = tile0 + tid;
    if (GROUPED) tl[tid] = (li < cnt) ? tokenlist[p * Tt + li] : tokenlist[p * Tt];
    else         tl[tid] = li;
  }
  __syncthreads();
  const int w = tid >> 6, lane = tid & 63;
  const int fr = lane & 15, fs = lane >> 4;
  const int wr = w >> 1, wc = w & 1;
  const int n0 = blockIdx.y * 128;
  const unsigned short* Bp0 = Bt + (size_t)p * NTOT * KTOT + (size_t)n0 * KTOT;
  // staging: unit u ; global (row u>>3, slot (u&7)^(row&7)) ; LDS linear at u*16B
  const unsigned short* srcA[2];
  #pragma unroll
  for (int i = 0; i < 2; ++i) {
    const int u = i * 256 + tid, r = u >> 3, sl = (u & 7) ^ (r & 7);
    srcA[i] = A + (size_t)tl[r] * KTOT + sl * 8;
  }
  const unsigned short* srcB[4];
  #pragma unroll
  for (int i = 0; i < 4; ++i) {
    const int u = i * 256 + tid, r = u >> 3, sl = (u & 7) ^ (r & 7);
    srcB[i] = Bp0 + (size_t)r * KTOT + sl * 8;
  }
  const int ldsW = w * 512;  // wave-uniform dest offset (shorts)
  // fragment read offsets (swizzled)
  int aoff[2][2], boff[4][2];
  #pragma unroll
  for (int m = 0; m < 2; ++m)
    #pragma unroll
    for (int kk = 0; kk < 2; ++kk)
      aoff[m][kk] = KSW(wr * 32 + m * 16 + fr, kk * 4 + fs);
  #pragma unroll
  for (int n = 0; n < 4; ++n)
    #pragma unroll
    for (int kk = 0; kk < 2; ++kk)
      boff[n][kk] = KSW(wc * 64 + n * 16 + fr, kk * 4 + fs);

#define STAGE(b, kb) do { \
    gload16(srcA[0] + (kb), &As[b][0] + ldsW); \
    gload16(srcA[1] + (kb), &As[b][0] + 2048 + ldsW); \
    gload16(srcB[0] + (kb), &Bs[b][0] + ldsW); \
    gload16(srcB[1] + (kb), &Bs[b][0] + 2048 + ldsW); \
    gload16(srcB[2] + (kb), &Bs[b][0] + 4096 + ldsW); \
    gload16(srcB[3] + (kb), &Bs[b][0] + 6144 + ldsW); \
  } while (0)

  f32x4 acc[2][4] = {};
  const int NS = KTOT / 64;
  STAGE(0, 0);
  for (int s = 0; s < NS; ++s) {
    const int buf = s & 1;
    if (s + 1 < NS) {
      STAGE(buf ^ 1, (s + 1) * 64);
      asm volatile("s_waitcnt vmcnt(6)" ::: "memory");   // current buf's 6 loads done
    } else {
      asm volatile("s_waitcnt vmcnt(0)" ::: "memory");
    }
    __builtin_amdgcn_s_barrier();
    __builtin_amdgcn_sched_barrier(0);
    const unsigned short* Ab = &As[buf][0];
    const unsigned short* Bb_ = &Bs[buf][0];
    bf16x8 a[2][2], b[4][2];
    #pragma unroll
    for (int m = 0; m < 2; ++m)
      #pragma unroll
      for (int kk = 0; kk < 2; ++kk)
        a[m][kk] = *(const bf16x8*)&Ab[aoff[m][kk]];
    #pragma unroll
    for (int n = 0; n < 4; ++n)
      #pragma unroll
      for (int kk = 0; kk < 2; ++kk)
        b[n][kk] = *(const bf16x8*)&Bb_[boff[n][kk]];
    #pragma unroll
    for (int kk = 0; kk < 2; ++kk)
      #pragma unroll
      for (int m = 0; m < 2; ++m)
        #pragma unroll
        for (int n = 0; n < 4; ++n)
          acc[m][n] = __builtin_amdgcn_mfma_f32_16x16x32_bf16(a[m][kk], b[n][kk], acc[m][n], 0, 0, 0);
    __builtin_amdgcn_s_barrier();   // reads of buf done before restage
  }
#undef STAGE

  // C/D layout: col = fr, row = fs*4 + j
  const float* bias_z = bias + (size_t)p * NTOT;
  #pragma unroll
  for (int m = 0; m < 2; ++m) {
    #pragma unroll
    for (int j = 0; j < 4; ++j) {
      const int rr = wr * 32 + m * 16 + fs * 4 + j;
      const int li = tile0 + rr;
      if (GROUPED && li >= cnt) continue;
      const int t = tl[rr];
      #pragma unroll
      for (int n = 0; n < 4; ++n) {
        const int c = n0 + wc * 64 + n * 16 + fr;
        const float v = acc[m][n][j] + bias_z[c];
        if (MODE == 0)      outf[(size_t)t * NTOT + c] = tanhf(v);
        else if (MODE == 1) outh[(size_t)t * NTOT + c] = bf16rn(v);
        else                outf[(size_t)t * NTOT + c] = v + resid[(size_t)t * NTOT + c];
      }
    }
  }
}

// ---------------------------------------------------------------- scores + argmax + flag + scatter (64 tokens/block)
__global__ __launch_bounds__(256) void k_score(const float* __restrict__ hidden,
    const float* __restrict__ Wo2, const float* __restrict__ bo2,
    int* __restrict__ idx, int* __restrict__ nflag, int* __restrict__ flagged,
    int* __restrict__ counts, int* __restrict__ tokenlist) {
  __shared__ float sW[DMm * Pp];
  __shared__ int lcnt[Pp], lbase[Pp];
  const int tid = threadIdx.x;
  for (int l = tid; l < DMm * Pp; l += 256) sW[l] = Wo2[l];
  if (tid < Pp) lcnt[tid] = 0;
  __syncthreads();
  const int wave = tid >> 6, lane = tid & 63;
  int tArr[16], pArr[16], sArr[16];
  #pragma unroll
  for (int it = 0; it < 16; ++it) {
    const int t = blockIdx.x * 64 + it * 4 + wave;
    const float4 h = *(const float4*)(hidden + (size_t)t * DMm + lane * 4);
    const int m = lane * 4;
    float part[Pp];
    #pragma unroll
    for (int pp = 0; pp < Pp; ++pp)
      part[pp] = h.x * sW[(m + 0) * Pp + pp] + h.y * sW[(m + 1) * Pp + pp]
               + h.z * sW[(m + 2) * Pp + pp] + h.w * sW[(m + 3) * Pp + pp];
    #pragma unroll
    for (int off = 32; off > 0; off >>= 1)
      #pragma unroll
      for (int pp = 0; pp < Pp; ++pp)
        part[pp] += __shfl_xor(part[pp], off);
    tArr[it] = -1;
    if (lane == 0) {
      float best = -1e30f, second = -1e30f;
      int bi = 0;
      #pragma unroll
      for (int pp = 0; pp < Pp; ++pp) {
        const float sc = part[pp] + bo2[pp];
        if (sc > best) { second = best; best = sc; bi = pp; }
        else if (sc > second) second = sc;
      }
      idx[t] = bi;
      if (best - second < BAND) {
        const int pos = atomicAdd(nflag, 1);
        flagged[pos] = t;            // rescue will scatter this token
      } else {
        tArr[it] = t; pArr[it] = bi;
        sArr[it] = atomicAdd(&lcnt[bi], 1);
      }
    }
  }
  __syncthreads();
  if (tid < Pp) lbase[tid] = atomicAdd(&counts[tid], lcnt[tid]);
  __syncthreads();
  #pragma unroll
  for (int it = 0; it < 16; ++it)
    if (tArr[it] >= 0)
      tokenlist[pArr[it] * Tt + lbase[pArr[it]] + sArr[it]] = tArr[it];
}

// ---------------------------------------------------------------- fp64 rescue (+ scatter of flagged tokens)
__global__ __launch_bounds__(256) void k_rescue(const float* __restrict__ x,
    const float* __restrict__ mk,
    const float* __restrict__ Wo1, const float* __restrict__ bo1,
    const float* __restrict__ Wo2, const float* __restrict__ bo2,
    const int* __restrict__ nflag, const int* __restrict__ flagged,
    int* __restrict__ idx, int* __restrict__ counts, int* __restrict__ tokenlist) {
  __shared__ double sx[Dd];
  __shared__ double th[DMm];
  __shared__ double red[4][12];
  const int nf = *nflag;
  const int tid = threadIdx.x;
  const int wv = tid >> 6, ln = tid & 63;
  for (int f = blockIdx.x; f < nf; f += gridDim.x) {
    const int t = flagged[f];
    const int s = t & (Ss - 1);
    for (int l = tid; l < Dd; l += 256) {
      const double xa = (s > 0)      ? (double)x[(size_t)(t - 1) * Dd + l] : 0.0;
      const double xb =                (double)x[(size_t)t * Dd + l];
      const double xc = (s < Ss - 1) ? (double)x[(size_t)(t + 1) * Dd + l] : 0.0;
      sx[l] = (double)mk[l] * xa + (double)mk[Dd + l] * xb + (double)mk[2 * Dd + l] * xc;
    }
    __syncthreads();
    {
      double a0 = 0, a1 = 0, a2 = 0, a3 = 0;
      const float* wcol = Wo1 + tid;
      for (int d = 0; d < Dd; d += 4) {
        a0 += sx[d + 0] * (double)wcol[(size_t)(d + 0) * DMm];
        a1 += sx[d + 1] * (double)wcol[(size_t)(d + 1) * DMm];
        a2 += sx[d + 2] * (double)wcol[(size_t)(d + 2) * DMm];
        a3 += sx[d + 3] * (double)wcol[(size_t)(d + 3) * DMm];
      }
      th[tid] = tanh(((a0 + a1) + (a2 + a3)) + (double)bo1[tid]);
    }
    __syncthreads();
    double pr[Pp];
    const double tv = th[tid];
    #pragma unroll
    for (int p = 0; p < Pp; ++p) pr[p] = tv * (double)Wo2[tid * Pp + p];
    #pragma unroll
    for (int off = 32; off > 0; off >>= 1)
      #pragma unroll
      for (int p = 0; p < Pp; ++p) pr[p] += __shfl_xor(pr[p], off);
    if (ln == 0) {
      #pragma unroll
      for (int p = 0; p < Pp; ++p) red[wv][p] = pr[p];
    }
    __syncthreads();
    if (tid == 0) {
      double best = -1e300; int bi = 0;
      #pragma unroll
      for (int p = 0; p < Pp; ++p) {
        const double sv = red[0][p] + red[1][p] + red[2][p] + red[3][p] + (double)bo2[p];
        if (sv > best) { best = sv; bi = p; }
      }
      idx[t] = bi;
      const int pos = atomicAdd(&counts[bi], 1);
      tokenlist[bi * Tt + pos] = t;
    }
    __syncthreads();
  }
}

// ---------------------------------------------------------------- in-place LayerNorm
__global__ __launch_bounds__(256) void k_ln(float* __restrict__ y,
    const float* __restrict__ gamma, const float* __restrict__ beta) {
  const int t = blockIdx.x;
  const int d = threadIdx.x << 2;
  float* row = y + (size_t)t * Dd;
  float4 v = *(float4*)(row + d);
  float s = v.x + v.y + v.z + v.w;
  float q = v.x * v.x + v.y * v.y + v.z * v.z + v.w * v.w;
  #pragma unroll
  for (int off = 32; off > 0; off >>= 1) {
    s += __shfl_xor(s, off);
    q += __shfl_xor(q, off);
  }
  __shared__ float ssum[4], sqq[4];
  const int wave = threadIdx.x >> 6, lane = threadIdx.x & 63;
  if (lane == 0) { ssum[wave] = s; sqq[wave] = q; }
  __syncthreads();
  s = ssum[0] + ssum[1] + ssum[2] + ssum[3];
  q = sqq[0] + sqq[1] + sqq[2] + sqq[3];
  const float mu = s * (1.f / Dd);
  const float var = q * (1.f / Dd) - mu * mu;
  const float inv = rsqrtf(var + EPSf);
  const float4 g = *(const float4*)(gamma + d);
  const float4 bt = *(const float4*)(beta + d);
  float4 o;
  o.x = (v.x - mu) * inv * g.x + bt.x;
  o.y = (v.y - mu) * inv * g.y + bt.y;
  o.z = (v.z - mu) * inv * g.z + bt.z;
  o.w = (v.w - mu) * inv * g.w + bt.w;
  *(float4*)(row + d) = o;
}

// ----------------------------------------------------------------
extern "C" void kernel_launch(void* const* d_in, const int* in_sizes, int n_in,
                              void* d_out, int out_size, void* d_ws, size_t ws_size,
                              hipStream_t stream) {
  (void)in_sizes; (void)n_in; (void)out_size; (void)ws_size;
  const float* x     = (const float*)d_in[0];
  const float* mk    = (const float*)d_in[1];
  const float* W1    = (const float*)d_in[2];
  const float* b1    = (const float*)d_in[3];
  const float* W2    = (const float*)d_in[4];
  const float* b2    = (const float*)d_in[5];
  const float* Wo1   = (const float*)d_in[6];
  const float* bo1   = (const float*)d_in[7];
  const float* Wo2   = (const float*)d_in[8];
  const float* bo2   = (const float*)d_in[9];
  const float* gamma = (const float*)d_in[10];
  const float* beta  = (const float*)d_in[11];
  float* out = (float*)d_out;

  size_t off = 0;
  auto alloc = [&](size_t bytes) -> void* {
    void* p = (char*)d_ws + off;
    off += (bytes + 255) & ~(size_t)255;
    return p;
  };
  unsigned short* xm_h   = (unsigned short*)alloc((size_t)Tt * Dd * 2);
  float*          hidden = (float*)alloc((size_t)Tt * DMm * 4);
  unsigned short* h1     = (unsigned short*)hidden;  // alias: hidden dead before h1 written
  unsigned short* W1t    = (unsigned short*)alloc((size_t)Pp * Dd * DMm * 2);
  unsigned short* W2t    = (unsigned short*)alloc((size_t)Pp * DMm * Dd * 2);
  unsigned short* Wo1t   = (unsigned short*)alloc((size_t)Dd * DMm * 2);
  int* idx      = (int*)alloc(Tt * 4);
  int* counts   = (int*)alloc(64 * 4);
  int* nflag    = counts + 16;
  int* flagged  = (int*)alloc(Tt * 4);
  int* tokenlist = (int*)alloc((size_t)Pp * Tt * 4);

  k_prep<<<Tt + (2 * Pp + 1) * 256, 256, 0, stream>>>(
      x, mk, xm_h, W1, W2, Wo1, W1t, W2t, Wo1t, counts);

  k_gemm<Dd, DMm, 0, false><<<dim3(Tt / 64, DMm / 128), 256, 0, stream>>>(
      xm_h, Wo1t, bo1, nullptr, hidden, nullptr, nullptr, nullptr);
  k_score<<<Tt / 64, 256, 0, stream>>>(hidden, Wo2, bo2, idx, nflag, flagged,
                                       counts, tokenlist);
  k_rescue<<<256, 256, 0, stream>>>(x, mk, Wo1, bo1, Wo2, bo2, nflag, flagged,
                                    idx, counts, tokenlist);

  k_gemm<Dd, DMm, 1, true><<<dim3(MAXTILES, DMm / 128), 256, 0, stream>>>(
      xm_h, W1t, b1, nullptr, nullptr, h1, counts, tokenlist);
  k_gemm<DMm, Dd, 2, true><<<dim3(MAXTILES, Dd / 128), 256, 0, stream>>>(
      h1, W2t, b2, x, out, nullptr, counts, tokenlist);
  k_ln<<<Tt, 256, 0, stream>>>(out, gamma, beta);
}

// Round 12
// 137.064 us; speedup vs baseline: 1.2442x; 1.2442x over previous
//
#include <hip/hip_runtime.h>
#include <math.h>

#define Ss 2048
#define Dd 1024
#define Pp 9
#define DMm 256
#define Tt 8192
#define EPSf 1e-5f
#define BAND 6e-3f       // fp64-rescue band for argmax ties

typedef __attribute__((ext_vector_type(8))) __bf16 bf16x8;
typedef __attribute__((ext_vector_type(4))) float f32x4;

#define GLOBAL_AS __attribute__((address_space(1)))
#define LDS_AS __attribute__((address_space(3)))

#define MAXTILES 137     // sum_p ceil(cnt_p/64) <= 8192/64 + 9

__device__ __forceinline__ unsigned short bf16rn(float f) {
  unsigned int u = __float_as_uint(f);
  unsigned int r = (u + 0x7fffu + ((u >> 16) & 1u)) >> 16;
  return (unsigned short)r;
}

__device__ __forceinline__ void gload16(const void* g, void* l) {
  __builtin_amdgcn_global_load_lds((const GLOBAL_AS unsigned int*)g,
                                   (LDS_AS unsigned int*)l, 16, 0, 0);
}

// bijective XCD-chunked block swizzle (m204): consecutive result values land
// on the SAME XCD (dispatch round-robins XCD = bx % 8).
__device__ __forceinline__ int xcd_swz(int bx, int nwg) {
  const int q = nwg >> 3, r = nwg & 7;
  const int xcd = bx & 7, loc = bx >> 3;
  return (xcd < r ? xcd * (q + 1) : r * (q + 1) + (xcd - r) * q) + loc;
}

// swizzled LDS short-offset, BK=64 rows (8 x 16B slots/row)
#define KSW(r, sl) (((r) << 6) + ((((sl) ^ ((r) & 7))) << 3))

// ---------------------------------------------------------------- mix -> bf16 (+ zero counts)
__global__ __launch_bounds__(256) void k_mix2(const float* __restrict__ x,
    const float* __restrict__ mk, unsigned short* __restrict__ xh,
    int* __restrict__ counts) {
  if (blockIdx.x == 0 && threadIdx.x < 64) counts[threadIdx.x] = 0;
  const int t = xcd_swz(blockIdx.x, Tt);   // XCD-chunked: x rows t-1..t+1 L2-local
  const int s = t & (Ss - 1);
  const int d = threadIdx.x << 2;
  const float* xc = x + (size_t)t * Dd + d;
  float4 vb = *(const float4*)xc;
  float4 va = make_float4(0.f, 0.f, 0.f, 0.f);
  float4 vc = make_float4(0.f, 0.f, 0.f, 0.f);
  if (s > 0)      va = *(const float4*)(xc - Dd);
  if (s < Ss - 1) vc = *(const float4*)(xc + Dd);
  const float4 k0 = *(const float4*)(mk + d);
  const float4 k1 = *(const float4*)(mk + Dd + d);
  const float4 k2 = *(const float4*)(mk + 2 * Dd + d);
  float4 o;
  o.x = k0.x * va.x + k1.x * vb.x + k2.x * vc.x;
  o.y = k0.y * va.y + k1.y * vb.y + k2.y * vc.y;
  o.z = k0.z * va.z + k1.z * vb.z + k2.z * vc.z;
  o.w = k0.w * va.w + k1.w * vb.w + k2.w * vc.w;
  ushort4 h;
  h.x = bf16rn(o.x); h.y = bf16rn(o.y); h.z = bf16rn(o.z); h.w = bf16rn(o.w);
  *(ushort4*)(xh + (size_t)t * Dd + d) = h;
}

// ---------------------------------------------------------------- all weight converts, dense grid (32,8,19)
__global__ __launch_bounds__(256) void k_cvt_all(
    const float* __restrict__ W1, const float* __restrict__ W2,
    const float* __restrict__ Wo1,
    unsigned short* __restrict__ W1t, unsigned short* __restrict__ W2t,
    unsigned short* __restrict__ Wo1t) {
  const int z = blockIdx.z;
  const float* in; unsigned short* outp; int R, C, r0, c0;
  if (z < Pp)            { in = W1;  outp = W1t;  R = Dd;  C = DMm;
                           r0 = blockIdx.x * 32; c0 = blockIdx.y * 32; }
  else if (z < 2 * Pp)   { in = W2;  outp = W2t;  R = DMm; C = Dd;
                           r0 = blockIdx.y * 32; c0 = blockIdx.x * 32; }
  else                   { in = Wo1; outp = Wo1t; R = Dd;  C = DMm;
                           r0 = blockIdx.x * 32; c0 = blockIdx.y * 32; }
  const int zi = (z < Pp) ? z : ((z < 2 * Pp) ? z - Pp : 0);
  const size_t zo = (size_t)zi * R * C;
  __shared__ float tile[32][33];
  const int tr = threadIdx.x >> 3, tc = (threadIdx.x & 7) << 2;
  float4 v = *(const float4*)(in + zo + (size_t)(r0 + tr) * C + c0 + tc);
  tile[tr][tc] = v.x; tile[tr][tc + 1] = v.y; tile[tr][tc + 2] = v.z; tile[tr][tc + 3] = v.w;
  __syncthreads();
  ushort4 h;
  h.x = bf16rn(tile[tc + 0][tr]); h.y = bf16rn(tile[tc + 1][tr]);
  h.z = bf16rn(tile[tc + 2][tr]); h.w = bf16rn(tile[tc + 3][tr]);
  *(ushort4*)(outp + zo + (size_t)(c0 + tr) * R + r0 + tc) = h;
}

// ---------------------------------------------------------------- pipelined MFMA GEMM, 64x128 tile, BK=64
// Packed grid + XCD swizzle: blocks with contiguous ti share B panels on one XCD.
// MODE 0: outf = tanh(acc+bias)   MODE 1: outh = bf16(acc+bias)   MODE 2: outf = acc+bias+resid
template<int KTOT, int NTOT, int MODE, bool GROUPED>
__global__ __launch_bounds__(256) void k_gemm(
    const unsigned short* __restrict__ A,
    const unsigned short* __restrict__ Bt,
    const float* __restrict__ bias,
    const float* __restrict__ resid,
    float* __restrict__ outf, unsigned short* __restrict__ outh,
    const int* __restrict__ counts, const int* __restrict__ tokenlist) {
  int p = 0, ti = xcd_swz(blockIdx.x, gridDim.x), cnt = Tt;
  if (GROUPED) {
    for (p = 0; p < Pp; ++p) {
      cnt = counts[p];
      const int nt = (cnt + 63) >> 6;
      if (ti < nt) break;
      ti -= nt;
    }
    if (p == Pp) return;
  }
  const int tile0 = ti * 64;
  __shared__ int tl[64];
  __shared__ __align__(16) unsigned short As[2][64 * 64];   // 2 x 8 KB
  __shared__ __align__(16) unsigned short Bs[2][128 * 64];  // 2 x 16 KB
  const int tid = threadIdx.x;
  if (tid < 64) {
    const int li = tile0 + tid;
    if (GROUPED) tl[tid] = (li < cnt) ? tokenlist[p * Tt + li] : tokenlist[p * Tt];
    else         tl[tid] = li;
  }
  __syncthreads();
  const int w = tid >> 6, lane = tid & 63;
  const int fr = lane & 15, fs = lane >> 4;
  const int wr = w >> 1, wc = w & 1;
  const int n0 = blockIdx.y * 128;
  const unsigned short* Bp0 = Bt + (size_t)p * NTOT * KTOT + (size_t)n0 * KTOT;
  // staging: unit u ; global (row u>>3, slot (u&7)^(row&7)) ; LDS linear at u*16B
  const unsigned short* srcA[2];
  #pragma unroll
  for (int i = 0; i < 2; ++i) {
    const int u = i * 256 + tid, r = u >> 3, sl = (u & 7) ^ (r & 7);
    srcA[i] = A + (size_t)tl[r] * KTOT + sl * 8;
  }
  const unsigned short* srcB[4];
  #pragma unroll
  for (int i = 0; i < 4; ++i) {
    const int u = i * 256 + tid, r = u >> 3, sl = (u & 7) ^ (r & 7);
    srcB[i] = Bp0 + (size_t)r * KTOT + sl * 8;
  }
  const int ldsW = w * 512;  // wave-uniform dest offset (shorts)
  // fragment read offsets (swizzled)
  int aoff[2][2], boff[4][2];
  #pragma unroll
  for (int m = 0; m < 2; ++m)
    #pragma unroll
    for (int kk = 0; kk < 2; ++kk)
      aoff[m][kk] = KSW(wr * 32 + m * 16 + fr, kk * 4 + fs);
  #pragma unroll
  for (int n = 0; n < 4; ++n)
    #pragma unroll
    for (int kk = 0; kk < 2; ++kk)
      boff[n][kk] = KSW(wc * 64 + n * 16 + fr, kk * 4 + fs);

#define STAGE(b, kb) do { \
    gload16(srcA[0] + (kb), &As[b][0] + ldsW); \
    gload16(srcA[1] + (kb), &As[b][0] + 2048 + ldsW); \
    gload16(srcB[0] + (kb), &Bs[b][0] + ldsW); \
    gload16(srcB[1] + (kb), &Bs[b][0] + 2048 + ldsW); \
    gload16(srcB[2] + (kb), &Bs[b][0] + 4096 + ldsW); \
    gload16(srcB[3] + (kb), &Bs[b][0] + 6144 + ldsW); \
  } while (0)

  f32x4 acc[2][4] = {};
  const int NS = KTOT / 64;
  STAGE(0, 0);
  for (int s = 0; s < NS; ++s) {
    const int buf = s & 1;
    if (s + 1 < NS) {
      STAGE(buf ^ 1, (s + 1) * 64);
      asm volatile("s_waitcnt vmcnt(6)" ::: "memory");   // current buf's 6 loads done
    } else {
      asm volatile("s_waitcnt vmcnt(0)" ::: "memory");
    }
    __builtin_amdgcn_s_barrier();
    __builtin_amdgcn_sched_barrier(0);
    const unsigned short* Ab = &As[buf][0];
    const unsigned short* Bb_ = &Bs[buf][0];
    bf16x8 a[2][2], b[4][2];
    #pragma unroll
    for (int m = 0; m < 2; ++m)
      #pragma unroll
      for (int kk = 0; kk < 2; ++kk)
        a[m][kk] = *(const bf16x8*)&Ab[aoff[m][kk]];
    #pragma unroll
    for (int n = 0; n < 4; ++n)
      #pragma unroll
      for (int kk = 0; kk < 2; ++kk)
        b[n][kk] = *(const bf16x8*)&Bb_[boff[n][kk]];
    #pragma unroll
    for (int kk = 0; kk < 2; ++kk)
      #pragma unroll
      for (int m = 0; m < 2; ++m)
        #pragma unroll
        for (int n = 0; n < 4; ++n)
          acc[m][n] = __builtin_amdgcn_mfma_f32_16x16x32_bf16(a[m][kk], b[n][kk], acc[m][n], 0, 0, 0);
    __builtin_amdgcn_s_barrier();   // reads of buf done before restage
  }
#undef STAGE

  // C/D layout: col = fr, row = fs*4 + j
  const float* bias_z = bias + (size_t)p * NTOT;
  #pragma unroll
  for (int m = 0; m < 2; ++m) {
    #pragma unroll
    for (int j = 0; j < 4; ++j) {
      const int rr = wr * 32 + m * 16 + fs * 4 + j;
      const int li = tile0 + rr;
      if (GROUPED && li >= cnt) continue;
      const int t = tl[rr];
      #pragma unroll
      for (int n = 0; n < 4; ++n) {
        const int c = n0 + wc * 64 + n * 16 + fr;
        const float v = acc[m][n][j] + bias_z[c];
        if (MODE == 0)      outf[(size_t)t * NTOT + c] = tanhf(v);
        else if (MODE == 1) outh[(size_t)t * NTOT + c] = bf16rn(v);
        else                outf[(size_t)t * NTOT + c] = v + resid[(size_t)t * NTOT + c];
      }
    }
  }
}

// ---------------------------------------------------------------- scores + argmax + near-tie flag (4 tokens/block)
__global__ __launch_bounds__(256) void k_score(const float* __restrict__ hidden,
    const float* __restrict__ Wo2, const float* __restrict__ bo2,
    int* __restrict__ idx, int* __restrict__ nflag, int* __restrict__ flagged) {
  __shared__ float sW[DMm * Pp];
  const int tid = threadIdx.x;
  for (int l = tid; l < DMm * Pp; l += 256) sW[l] = Wo2[l];
  __syncthreads();
  const int wave = tid >> 6, lane = tid & 63;
  const int t = blockIdx.x * 4 + wave;
  const float4 h = *(const float4*)(hidden + (size_t)t * DMm + lane * 4);
  const int m = lane * 4;
  float part[Pp];
  #pragma unroll
  for (int pp = 0; pp < Pp; ++pp)
    part[pp] = h.x * sW[(m + 0) * Pp + pp] + h.y * sW[(m + 1) * Pp + pp]
             + h.z * sW[(m + 2) * Pp + pp] + h.w * sW[(m + 3) * Pp + pp];
  #pragma unroll
  for (int off = 32; off > 0; off >>= 1)
    #pragma unroll
    for (int pp = 0; pp < Pp; ++pp)
      part[pp] += __shfl_xor(part[pp], off);
  if (lane == 0) {
    float best = -1e30f, second = -1e30f;
    int bi = 0;
    #pragma unroll
    for (int pp = 0; pp < Pp; ++pp) {
      const float sc = part[pp] + bo2[pp];
      if (sc > best) { second = best; best = sc; bi = pp; }
      else if (sc > second) second = sc;
    }
    idx[t] = bi;
    if (best - second < BAND) {
      const int pos = atomicAdd(nflag, 1);
      flagged[pos] = t;
    }
  }
}

// ---------------------------------------------------------------- fp64 rescue (parallelized)
__global__ __launch_bounds__(256) void k_rescue(const float* __restrict__ x,
    const float* __restrict__ mk,
    const float* __restrict__ Wo1, const float* __restrict__ bo1,
    const float* __restrict__ Wo2, const float* __restrict__ bo2,
    const int* __restrict__ nflag, const int* __restrict__ flagged,
    int* __restrict__ idx) {
  __shared__ double sx[Dd];
  __shared__ double th[DMm];
  __shared__ double red[4][12];
  const int nf = *nflag;
  const int tid = threadIdx.x;
  const int wv = tid >> 6, ln = tid & 63;
  for (int f = blockIdx.x; f < nf; f += gridDim.x) {
    const int t = flagged[f];
    const int s = t & (Ss - 1);
    for (int l = tid; l < Dd; l += 256) {
      const double xa = (s > 0)      ? (double)x[(size_t)(t - 1) * Dd + l] : 0.0;
      const double xb =                (double)x[(size_t)t * Dd + l];
      const double xc = (s < Ss - 1) ? (double)x[(size_t)(t + 1) * Dd + l] : 0.0;
      sx[l] = (double)mk[l] * xa + (double)mk[Dd + l] * xb + (double)mk[2 * Dd + l] * xc;
    }
    __syncthreads();
    {
      double a0 = 0, a1 = 0, a2 = 0, a3 = 0;
      const float* wcol = Wo1 + tid;
      for (int d = 0; d < Dd; d += 4) {
        a0 += sx[d + 0] * (double)wcol[(size_t)(d + 0) * DMm];
        a1 += sx[d + 1] * (double)wcol[(size_t)(d + 1) * DMm];
        a2 += sx[d + 2] * (double)wcol[(size_t)(d + 2) * DMm];
        a3 += sx[d + 3] * (double)wcol[(size_t)(d + 3) * DMm];
      }
      th[tid] = tanh(((a0 + a1) + (a2 + a3)) + (double)bo1[tid]);
    }
    __syncthreads();
    double pr[Pp];
    const double tv = th[tid];
    #pragma unroll
    for (int p = 0; p < Pp; ++p) pr[p] = tv * (double)Wo2[tid * Pp + p];
    #pragma unroll
    for (int off = 32; off > 0; off >>= 1)
      #pragma unroll
      for (int p = 0; p < Pp; ++p) pr[p] += __shfl_xor(pr[p], off);
    if (ln == 0) {
      #pragma unroll
      for (int p = 0; p < Pp; ++p) red[wv][p] = pr[p];
    }
    __syncthreads();
    if (tid == 0) {
      double best = -1e300; int bi = 0;
      #pragma unroll
      for (int p = 0; p < Pp; ++p) {
        const double sv = red[0][p] + red[1][p] + red[2][p] + red[3][p] + (double)bo2[p];
        if (sv > best) { best = sv; bi = p; }
      }
      idx[t] = bi;
    }
    __syncthreads();
  }
}

// ---------------------------------------------------------------- group tokens by path (LDS histogram)
__global__ __launch_bounds__(256) void k_scatter(const int* __restrict__ idx,
    int* __restrict__ counts, int* __restrict__ tokenlist) {
  __shared__ int lcnt[Pp], lbase[Pp];
  const int tid = threadIdx.x;
  if (tid < Pp) lcnt[tid] = 0;
  __syncthreads();
  const int t = blockIdx.x * 256 + tid;
  const int p = idx[t];
  const int slot = atomicAdd(&lcnt[p], 1);     // LDS atomic: cheap
  __syncthreads();
  if (tid < Pp) lbase[tid] = atomicAdd(&counts[tid], lcnt[tid]);  // 9 global atomics/block
  __syncthreads();
  tokenlist[p * Tt + lbase[p] + slot] = t;
}

// ---------------------------------------------------------------- in-place LayerNorm
__global__ __launch_bounds__(256) void k_ln(float* __restrict__ y,
    const float* __restrict__ gamma, const float* __restrict__ beta) {
  const int t = blockIdx.x;
  const int d = threadIdx.x << 2;
  float* row = y + (size_t)t * Dd;
  float4 v = *(float4*)(row + d);
  float s = v.x + v.y + v.z + v.w;
  float q = v.x * v.x + v.y * v.y + v.z * v.z + v.w * v.w;
  #pragma unroll
  for (int off = 32; off > 0; off >>= 1) {
    s += __shfl_xor(s, off);
    q += __shfl_xor(q, off);
  }
  __shared__ float ssum[4], sqq[4];
  const int wave = threadIdx.x >> 6, lane = threadIdx.x & 63;
  if (lane == 0) { ssum[wave] = s; sqq[wave] = q; }
  __syncthreads();
  s = ssum[0] + ssum[1] + ssum[2] + ssum[3];
  q = sqq[0] + sqq[1] + sqq[2] + sqq[3];
  const float mu = s * (1.f / Dd);
  const float var = q * (1.f / Dd) - mu * mu;
  const float inv = rsqrtf(var + EPSf);
  const float4 g = *(const float4*)(gamma + d);
  const float4 bt = *(const float4*)(beta + d);
  float4 o;
  o.x = (v.x - mu) * inv * g.x + bt.x;
  o.y = (v.y - mu) * inv * g.y + bt.y;
  o.z = (v.z - mu) * inv * g.z + bt.z;
  o.w = (v.w - mu) * inv * g.w + bt.w;
  *(float4*)(row + d) = o;
}

// ----------------------------------------------------------------
extern "C" void kernel_launch(void* const* d_in, const int* in_sizes, int n_in,
                              void* d_out, int out_size, void* d_ws, size_t ws_size,
                              hipStream_t stream) {
  (void)in_sizes; (void)n_in; (void)out_size; (void)ws_size;
  const float* x     = (const float*)d_in[0];
  const float* mk    = (const float*)d_in[1];
  const float* W1    = (const float*)d_in[2];
  const float* b1    = (const float*)d_in[3];
  const float* W2    = (const float*)d_in[4];
  const float* b2    = (const float*)d_in[5];
  const float* Wo1   = (const float*)d_in[6];
  const float* bo1   = (const float*)d_in[7];
  const float* Wo2   = (const float*)d_in[8];
  const float* bo2   = (const float*)d_in[9];
  const float* gamma = (const float*)d_in[10];
  const float* beta  = (const float*)d_in[11];
  float* out = (float*)d_out;

  size_t off = 0;
  auto alloc = [&](size_t bytes) -> void* {
    void* p = (char*)d_ws + off;
    off += (bytes + 255) & ~(size_t)255;
    return p;
  };
  unsigned short* xm_h   = (unsigned short*)alloc((size_t)Tt * Dd * 2);
  float*          hidden = (float*)alloc((size_t)Tt * DMm * 4);
  unsigned short* h1     = (unsigned short*)hidden;  // alias: hidden dead before h1 written
  unsigned short* W1t    = (unsigned short*)alloc((size_t)Pp * Dd * DMm * 2);
  unsigned short* W2t    = (unsigned short*)alloc((size_t)Pp * DMm * Dd * 2);
  unsigned short* Wo1t   = (unsigned short*)alloc((size_t)Dd * DMm * 2);
  int* idx      = (int*)alloc(Tt * 4);
  int* counts   = (int*)alloc(64 * 4);
  int* nflag    = counts + 16;
  int* flagged  = (int*)alloc(Tt * 4);
  int* tokenlist = (int*)alloc((size_t)Pp * Tt * 4);

  k_mix2<<<Tt, 256, 0, stream>>>(x, mk, xm_h, counts);
  k_cvt_all<<<dim3(32, 8, 2 * Pp + 1), 256, 0, stream>>>(W1, W2, Wo1, W1t, W2t, Wo1t);

  k_gemm<Dd, DMm, 0, false><<<dim3(Tt / 64, DMm / 128), 256, 0, stream>>>(
      xm_h, Wo1t, bo1, nullptr, hidden, nullptr, nullptr, nullptr);
  k_score<<<Tt / 4, 256, 0, stream>>>(hidden, Wo2, bo2, idx, nflag, flagged);
  k_rescue<<<256, 256, 0, stream>>>(x, mk, Wo1, bo1, Wo2, bo2, nflag, flagged, idx);
  k_scatter<<<Tt / 256, 256, 0, stream>>>(idx, counts, tokenlist);

  k_gemm<Dd, DMm, 1, true><<<dim3(MAXTILES, DMm / 128), 256, 0, stream>>>(
      xm_h, W1t, b1, nullptr, nullptr, h1, counts, tokenlist);
  k_gemm<DMm, Dd, 2, true><<<dim3(MAXTILES, Dd / 128), 256, 0, stream>>>(
      h1, W2t, b2, x, out, nullptr, counts, tokenlist);
  k_ln<<<Tt, 256, 0, stream>>>(out, gamma, beta);
}

// Round 13
// 132.382 us; speedup vs baseline: 1.2882x; 1.0354x over previous
//
#include <hip/hip_runtime.h>
#include <math.h>

#define Ss 2048
#define Dd 1024
#define Pp 9
#define DMm 256
#define Tt 8192
#define EPSf 1e-5f
#define BAND 6e-3f       // fp64-rescue band for argmax ties

typedef __attribute__((ext_vector_type(8))) __bf16 bf16x8;
typedef __attribute__((ext_vector_type(4))) float f32x4;

#define GLOBAL_AS __attribute__((address_space(1)))
#define LDS_AS __attribute__((address_space(3)))

#define MAXTILES 137     // sum_p ceil(cnt_p/64) <= 8192/64 + 9
#define MAXT32   265     // sum_p ceil(cnt_p/32) <= 8192/32 + 9

__device__ __forceinline__ unsigned short bf16rn(float f) {
  unsigned int u = __float_as_uint(f);
  unsigned int r = (u + 0x7fffu + ((u >> 16) & 1u)) >> 16;
  return (unsigned short)r;
}

__device__ __forceinline__ void gload16(const void* g, void* l) {
  __builtin_amdgcn_global_load_lds((const GLOBAL_AS unsigned int*)g,
                                   (LDS_AS unsigned int*)l, 16, 0, 0);
}

// bijective XCD-chunked block swizzle (m204): consecutive result values land
// on the SAME XCD (dispatch round-robins XCD = bx % 8).
__device__ __forceinline__ int xcd_swz(int bx, int nwg) {
  const int q = nwg >> 3, r = nwg & 7;
  const int xcd = bx & 7, loc = bx >> 3;
  return (xcd < r ? xcd * (q + 1) : r * (q + 1) + (xcd - r) * q) + loc;
}

// swizzled LDS short-offset, BK=64 rows (8 x 16B slots/row)
#define KSW(r, sl) (((r) << 6) + ((((sl) ^ ((r) & 7))) << 3))

// ---------------------------------------------------------------- prep: mix -> bf16 (XCD-chunked) + weight cvt/T + zero counts
__global__ __launch_bounds__(256) void k_prep(const float* __restrict__ x,
    const float* __restrict__ mk, unsigned short* __restrict__ xh,
    const float* __restrict__ W1, const float* __restrict__ W2,
    const float* __restrict__ Wo1,
    unsigned short* __restrict__ W1t, unsigned short* __restrict__ W2t,
    unsigned short* __restrict__ Wo1t, int* __restrict__ counts) {
  const int bid = blockIdx.x;
  if (bid < Tt) {
    if (bid == 0 && threadIdx.x < 64) counts[threadIdx.x] = 0;
    const int t = xcd_swz(bid, Tt);    // XCD-chunked: x rows t-1..t+1 L2-local
    const int s = t & (Ss - 1);
    const int d = threadIdx.x << 2;
    const float* xc = x + (size_t)t * Dd + d;
    float4 vb = *(const float4*)xc;
    float4 va = make_float4(0.f, 0.f, 0.f, 0.f);
    float4 vc = make_float4(0.f, 0.f, 0.f, 0.f);
    if (s > 0)      va = *(const float4*)(xc - Dd);
    if (s < Ss - 1) vc = *(const float4*)(xc + Dd);
    const float4 k0 = *(const float4*)(mk + d);
    const float4 k1 = *(const float4*)(mk + Dd + d);
    const float4 k2 = *(const float4*)(mk + 2 * Dd + d);
    float4 o;
    o.x = k0.x * va.x + k1.x * vb.x + k2.x * vc.x;
    o.y = k0.y * va.y + k1.y * vb.y + k2.y * vc.y;
    o.z = k0.z * va.z + k1.z * vb.z + k2.z * vc.z;
    o.w = k0.w * va.w + k1.w * vb.w + k2.w * vc.w;
    ushort4 h;
    h.x = bf16rn(o.x); h.y = bf16rn(o.y); h.z = bf16rn(o.z); h.w = bf16rn(o.w);
    *(ushort4*)(xh + (size_t)t * Dd + d) = h;
    return;
  }
  // weight convert+transpose: i in [0, 19*256)
  const int i = bid - Tt;
  const int z = i >> 8, rem = i & 255;
  const int bx = rem & 31, by = rem >> 5;
  const float* in; unsigned short* outp; int R, C, r0, c0;
  if (z < Pp)          { in = W1;  outp = W1t;  R = Dd;  C = DMm; r0 = bx * 32; c0 = by * 32; }
  else if (z < 2 * Pp) { in = W2;  outp = W2t;  R = DMm; C = Dd;  r0 = by * 32; c0 = bx * 32; }
  else                 { in = Wo1; outp = Wo1t; R = Dd;  C = DMm; r0 = bx * 32; c0 = by * 32; }
  const int zi = (z < Pp) ? z : ((z < 2 * Pp) ? z - Pp : 0);
  const size_t zo = (size_t)zi * R * C;
  __shared__ float tile[32][33];
  const int tr = threadIdx.x >> 3, tc = (threadIdx.x & 7) << 2;
  float4 v = *(const float4*)(in + zo + (size_t)(r0 + tr) * C + c0 + tc);
  tile[tr][tc] = v.x; tile[tr][tc + 1] = v.y; tile[tr][tc + 2] = v.z; tile[tr][tc + 3] = v.w;
  __syncthreads();
  ushort4 h;
  h.x = bf16rn(tile[tc + 0][tr]); h.y = bf16rn(tile[tc + 1][tr]);
  h.z = bf16rn(tile[tc + 2][tr]); h.w = bf16rn(tile[tc + 3][tr]);
  *(ushort4*)(outp + zo + (size_t)(c0 + tr) * R + r0 + tc) = h;
}

// ---------------------------------------------------------------- pipelined MFMA GEMM, TMx128 tile, BK=64, XCD-swizzled packed grid
// MODE 0: outf = tanh(acc+bias)   MODE 1: outh = bf16(acc+bias)   MODE 2: outf = acc+bias+resid
template<int KTOT, int NTOT, int MODE, bool GROUPED, int TM>
__global__ __launch_bounds__(256) void k_gemm(
    const unsigned short* __restrict__ A,
    const unsigned short* __restrict__ Bt,
    const float* __restrict__ bias,
    const float* __restrict__ resid,
    float* __restrict__ outf, unsigned short* __restrict__ outh,
    const int* __restrict__ counts, const int* __restrict__ tokenlist) {
  constexpr int MM = TM / 32;            // A fragments / loads per thread
  int p = 0, ti = xcd_swz(blockIdx.x, gridDim.x), cnt = Tt;
  if (GROUPED) {
    for (p = 0; p < Pp; ++p) {
      cnt = counts[p];
      const int nt = (cnt + TM - 1) / TM;
      if (ti < nt) break;
      ti -= nt;
    }
    if (p == Pp) return;
  }
  const int tile0 = ti * TM;
  __shared__ int tl[TM];
  __shared__ __align__(16) unsigned short As[2][TM * 64];
  __shared__ __align__(16) unsigned short Bs[2][128 * 64];
  const int tid = threadIdx.x;
  if (tid < TM) {
    const int li = tile0 + tid;
    if (GROUPED) tl[tid] = (li < cnt) ? tokenlist[p * Tt + li] : tokenlist[p * Tt];
    else         tl[tid] = li;
  }
  __syncthreads();
  const int w = tid >> 6, lane = tid & 63;
  const int fr = lane & 15, fs = lane >> 4;
  const int wr = w >> 1, wc = w & 1;
  const int n0 = blockIdx.y * 128;
  const unsigned short* Bp0 = Bt + (size_t)p * NTOT * KTOT + (size_t)n0 * KTOT;
  const unsigned short* srcA[MM];
  #pragma unroll
  for (int i = 0; i < MM; ++i) {
    const int u = i * 256 + tid, r = u >> 3, sl = (u & 7) ^ (r & 7);
    srcA[i] = A + (size_t)tl[r] * KTOT + sl * 8;
  }
  const unsigned short* srcB[4];
  #pragma unroll
  for (int i = 0; i < 4; ++i) {
    const int u = i * 256 + tid, r = u >> 3, sl = (u & 7) ^ (r & 7);
    srcB[i] = Bp0 + (size_t)r * KTOT + sl * 8;
  }
  const int ldsW = w * 512;  // wave-uniform dest offset (shorts)
  int aoff[MM][2], boff[4][2];
  #pragma unroll
  for (int m = 0; m < MM; ++m)
    #pragma unroll
    for (int kk = 0; kk < 2; ++kk)
      aoff[m][kk] = KSW(wr * (TM / 2) + m * 16 + fr, kk * 4 + fs);
  #pragma unroll
  for (int n = 0; n < 4; ++n)
    #pragma unroll
    for (int kk = 0; kk < 2; ++kk)
      boff[n][kk] = KSW(wc * 64 + n * 16 + fr, kk * 4 + fs);

#define STAGE(b, kb) do { \
    _Pragma("unroll") \
    for (int i = 0; i < MM; ++i) \
      gload16(srcA[i] + (kb), &As[b][0] + i * 2048 + ldsW); \
    gload16(srcB[0] + (kb), &Bs[b][0] + ldsW); \
    gload16(srcB[1] + (kb), &Bs[b][0] + 2048 + ldsW); \
    gload16(srcB[2] + (kb), &Bs[b][0] + 4096 + ldsW); \
    gload16(srcB[3] + (kb), &Bs[b][0] + 6144 + ldsW); \
  } while (0)

  f32x4 acc[MM][4] = {};
  const int NS = KTOT / 64;
  STAGE(0, 0);
  for (int s = 0; s < NS; ++s) {
    const int buf = s & 1;
    if (s + 1 < NS) {
      STAGE(buf ^ 1, (s + 1) * 64);
      if (TM == 64) asm volatile("s_waitcnt vmcnt(6)" ::: "memory");
      else          asm volatile("s_waitcnt vmcnt(5)" ::: "memory");
    } else {
      asm volatile("s_waitcnt vmcnt(0)" ::: "memory");
    }
    __builtin_amdgcn_s_barrier();
    __builtin_amdgcn_sched_barrier(0);
    const unsigned short* Ab = &As[buf][0];
    const unsigned short* Bb_ = &Bs[buf][0];
    bf16x8 a[MM][2], b[4][2];
    #pragma unroll
    for (int m = 0; m < MM; ++m)
      #pragma unroll
      for (int kk = 0; kk < 2; ++kk)
        a[m][kk] = *(const bf16x8*)&Ab[aoff[m][kk]];
    #pragma unroll
    for (int n = 0; n < 4; ++n)
      #pragma unroll
      for (int kk = 0; kk < 2; ++kk)
        b[n][kk] = *(const bf16x8*)&Bb_[boff[n][kk]];
    #pragma unroll
    for (int kk = 0; kk < 2; ++kk)
      #pragma unroll
      for (int m = 0; m < MM; ++m)
        #pragma unroll
        for (int n = 0; n < 4; ++n)
          acc[m][n] = __builtin_amdgcn_mfma_f32_16x16x32_bf16(a[m][kk], b[n][kk], acc[m][n], 0, 0, 0);
    __builtin_amdgcn_s_barrier();   // reads of buf done before restage
  }
#undef STAGE

  // C/D layout: col = fr, row = fs*4 + j
  const float* bias_z = bias + (size_t)p * NTOT;
  #pragma unroll
  for (int m = 0; m < MM; ++m) {
    #pragma unroll
    for (int j = 0; j < 4; ++j) {
      const int rr = wr * (TM / 2) + m * 16 + fs * 4 + j;
      const int li = tile0 + rr;
      if (GROUPED && li >= cnt) continue;
      const int t = tl[rr];
      #pragma unroll
      for (int n = 0; n < 4; ++n) {
        const int c = n0 + wc * 64 + n * 16 + fr;
        const float v = acc[m][n][j] + bias_z[c];
        if (MODE == 0)      outf[(size_t)t * NTOT + c] = tanhf(v);
        else if (MODE == 1) outh[(size_t)t * NTOT + c] = bf16rn(v);
        else                outf[(size_t)t * NTOT + c] = v + resid[(size_t)t * NTOT + c];
      }
    }
  }
}

// ---------------------------------------------------------------- scores + argmax + near-tie flag (4 tokens/block)
__global__ __launch_bounds__(256) void k_score(const float* __restrict__ hidden,
    const float* __restrict__ Wo2, const float* __restrict__ bo2,
    int* __restrict__ idx, int* __restrict__ nflag, int* __restrict__ flagged) {
  __shared__ float sW[DMm * Pp];
  const int tid = threadIdx.x;
  for (int l = tid; l < DMm * Pp; l += 256) sW[l] = Wo2[l];
  __syncthreads();
  const int wave = tid >> 6, lane = tid & 63;
  const int t = blockIdx.x * 4 + wave;
  const float4 h = *(const float4*)(hidden + (size_t)t * DMm + lane * 4);
  const int m = lane * 4;
  float part[Pp];
  #pragma unroll
  for (int pp = 0; pp < Pp; ++pp)
    part[pp] = h.x * sW[(m + 0) * Pp + pp] + h.y * sW[(m + 1) * Pp + pp]
             + h.z * sW[(m + 2) * Pp + pp] + h.w * sW[(m + 3) * Pp + pp];
  #pragma unroll
  for (int off = 32; off > 0; off >>= 1)
    #pragma unroll
    for (int pp = 0; pp < Pp; ++pp)
      part[pp] += __shfl_xor(part[pp], off);
  if (lane == 0) {
    float best = -1e30f, second = -1e30f;
    int bi = 0;
    #pragma unroll
    for (int pp = 0; pp < Pp; ++pp) {
      const float sc = part[pp] + bo2[pp];
      if (sc > best) { second = best; best = sc; bi = pp; }
      else if (sc > second) second = sc;
    }
    idx[t] = bi;
    if (best - second < BAND) {
      const int pos = atomicAdd(nflag, 1);
      flagged[pos] = t;
    }
  }
}

// ---------------------------------------------------------------- fp64 rescue (parallelized)
__global__ __launch_bounds__(256) void k_rescue(const float* __restrict__ x,
    const float* __restrict__ mk,
    const float* __restrict__ Wo1, const float* __restrict__ bo1,
    const float* __restrict__ Wo2, const float* __restrict__ bo2,
    const int* __restrict__ nflag, const int* __restrict__ flagged,
    int* __restrict__ idx) {
  __shared__ double sx[Dd];
  __shared__ double th[DMm];
  __shared__ double red[4][12];
  const int nf = *nflag;
  const int tid = threadIdx.x;
  const int wv = tid >> 6, ln = tid & 63;
  for (int f = blockIdx.x; f < nf; f += gridDim.x) {
    const int t = flagged[f];
    const int s = t & (Ss - 1);
    for (int l = tid; l < Dd; l += 256) {
      const double xa = (s > 0)      ? (double)x[(size_t)(t - 1) * Dd + l] : 0.0;
      const double xb =                (double)x[(size_t)t * Dd + l];
      const double xc = (s < Ss - 1) ? (double)x[(size_t)(t + 1) * Dd + l] : 0.0;
      sx[l] = (double)mk[l] * xa + (double)mk[Dd + l] * xb + (double)mk[2 * Dd + l] * xc;
    }
    __syncthreads();
    {
      double a0 = 0, a1 = 0, a2 = 0, a3 = 0;
      const float* wcol = Wo1 + tid;
      for (int d = 0; d < Dd; d += 4) {
        a0 += sx[d + 0] * (double)wcol[(size_t)(d + 0) * DMm];
        a1 += sx[d + 1] * (double)wcol[(size_t)(d + 1) * DMm];
        a2 += sx[d + 2] * (double)wcol[(size_t)(d + 2) * DMm];
        a3 += sx[d + 3] * (double)wcol[(size_t)(d + 3) * DMm];
      }
      th[tid] = tanh(((a0 + a1) + (a2 + a3)) + (double)bo1[tid]);
    }
    __syncthreads();
    double pr[Pp];
    const double tv = th[tid];
    #pragma unroll
    for (int p = 0; p < Pp; ++p) pr[p] = tv * (double)Wo2[tid * Pp + p];
    #pragma unroll
    for (int off = 32; off > 0; off >>= 1)
      #pragma unroll
      for (int p = 0; p < Pp; ++p) pr[p] += __shfl_xor(pr[p], off);
    if (ln == 0) {
      #pragma unroll
      for (int p = 0; p < Pp; ++p) red[wv][p] = pr[p];
    }
    __syncthreads();
    if (tid == 0) {
      double best = -1e300; int bi = 0;
      #pragma unroll
      for (int p = 0; p < Pp; ++p) {
        const double sv = red[0][p] + red[1][p] + red[2][p] + red[3][p] + (double)bo2[p];
        if (sv > best) { best = sv; bi = p; }
      }
      idx[t] = bi;
    }
    __syncthreads();
  }
}

// ---------------------------------------------------------------- group tokens by path (LDS histogram)
__global__ __launch_bounds__(256) void k_scatter(const int* __restrict__ idx,
    int* __restrict__ counts, int* __restrict__ tokenlist) {
  __shared__ int lcnt[Pp], lbase[Pp];
  const int tid = threadIdx.x;
  if (tid < Pp) lcnt[tid] = 0;
  __syncthreads();
  const int t = blockIdx.x * 256 + tid;
  const int p = idx[t];
  const int slot = atomicAdd(&lcnt[p], 1);     // LDS atomic: cheap
  __syncthreads();
  if (tid < Pp) lbase[tid] = atomicAdd(&counts[tid], lcnt[tid]);  // 9 global atomics/block
  __syncthreads();
  tokenlist[p * Tt + lbase[p] + slot] = t;
}

// ---------------------------------------------------------------- in-place LayerNorm
__global__ __launch_bounds__(256) void k_ln(float* __restrict__ y,
    const float* __restrict__ gamma, const float* __restrict__ beta) {
  const int t = blockIdx.x;
  const int d = threadIdx.x << 2;
  float* row = y + (size_t)t * Dd;
  float4 v = *(float4*)(row + d);
  float s = v.x + v.y + v.z + v.w;
  float q = v.x * v.x + v.y * v.y + v.z * v.z + v.w * v.w;
  #pragma unroll
  for (int off = 32; off > 0; off >>= 1) {
    s += __shfl_xor(s, off);
    q += __shfl_xor(q, off);
  }
  __shared__ float ssum[4], sqq[4];
  const int wave = threadIdx.x >> 6, lane = threadIdx.x & 63;
  if (lane == 0) { ssum[wave] = s; sqq[wave] = q; }
  __syncthreads();
  s = ssum[0] + ssum[1] + ssum[2] + ssum[3];
  q = sqq[0] + sqq[1] + sqq[2] + sqq[3];
  const float mu = s * (1.f / Dd);
  const float var = q * (1.f / Dd) - mu * mu;
  const float inv = rsqrtf(var + EPSf);
  const float4 g = *(const float4*)(gamma + d);
  const float4 bt = *(const float4*)(beta + d);
  float4 o;
  o.x = (v.x - mu) * inv * g.x + bt.x;
  o.y = (v.y - mu) * inv * g.y + bt.y;
  o.z = (v.z - mu) * inv * g.z + bt.z;
  o.w = (v.w - mu) * inv * g.w + bt.w;
  *(float4*)(row + d) = o;
}

// ----------------------------------------------------------------
extern "C" void kernel_launch(void* const* d_in, const int* in_sizes, int n_in,
                              void* d_out, int out_size, void* d_ws, size_t ws_size,
                              hipStream_t stream) {
  (void)in_sizes; (void)n_in; (void)out_size; (void)ws_size;
  const float* x     = (const float*)d_in[0];
  const float* mk    = (const float*)d_in[1];
  const float* W1    = (const float*)d_in[2];
  const float* b1    = (const float*)d_in[3];
  const float* W2    = (const float*)d_in[4];
  const float* b2    = (const float*)d_in[5];
  const float* Wo1   = (const float*)d_in[6];
  const float* bo1   = (const float*)d_in[7];
  const float* Wo2   = (const float*)d_in[8];
  const float* bo2   = (const float*)d_in[9];
  const float* gamma = (const float*)d_in[10];
  const float* beta  = (const float*)d_in[11];
  float* out = (float*)d_out;

  size_t off = 0;
  auto alloc = [&](size_t bytes) -> void* {
    void* p = (char*)d_ws + off;
    off += (bytes + 255) & ~(size_t)255;
    return p;
  };
  unsigned short* xm_h   = (unsigned short*)alloc((size_t)Tt * Dd * 2);
  float*          hidden = (float*)alloc((size_t)Tt * DMm * 4);
  unsigned short* h1     = (unsigned short*)hidden;  // alias: hidden dead before h1 written
  unsigned short* W1t    = (unsigned short*)alloc((size_t)Pp * Dd * DMm * 2);
  unsigned short* W2t    = (unsigned short*)alloc((size_t)Pp * DMm * Dd * 2);
  unsigned short* Wo1t   = (unsigned short*)alloc((size_t)Dd * DMm * 2);
  int* idx      = (int*)alloc(Tt * 4);
  int* counts   = (int*)alloc(64 * 4);
  int* nflag    = counts + 16;
  int* flagged  = (int*)alloc(Tt * 4);
  int* tokenlist = (int*)alloc((size_t)Pp * Tt * 4);

  k_prep<<<Tt + (2 * Pp + 1) * 256, 256, 0, stream>>>(
      x, mk, xm_h, W1, W2, Wo1, W1t, W2t, Wo1t, counts);

  k_gemm<Dd, DMm, 0, false, 32><<<dim3(Tt / 32, DMm / 128), 256, 0, stream>>>(
      xm_h, Wo1t, bo1, nullptr, hidden, nullptr, nullptr, nullptr);
  k_score<<<Tt / 4, 256, 0, stream>>>(hidden, Wo2, bo2, idx, nflag, flagged);
  k_rescue<<<256, 256, 0, stream>>>(x, mk, Wo1, bo1, Wo2, bo2, nflag, flagged, idx);
  k_scatter<<<Tt / 256, 256, 0, stream>>>(idx, counts, tokenlist);

  k_gemm<Dd, DMm, 1, true, 32><<<dim3(MAXT32, DMm / 128), 256, 0, stream>>>(
      xm_h, W1t, b1, nullptr, nullptr, h1, counts, tokenlist);
  k_gemm<DMm, Dd, 2, true, 64><<<dim3(MAXTILES, Dd / 128), 256, 0, stream>>>(
      h1, W2t, b2, x, out, nullptr, counts, tokenlist);
  k_ln<<<Tt, 256, 0, stream>>>(out, gamma, beta);
}

// Round 14
// 127.804 us; speedup vs baseline: 1.3343x; 1.0358x over previous
//
#include <hip/hip_runtime.h>
#include <math.h>

#define Ss 2048
#define Dd 1024
#define Pp 9
#define DMm 256
#define Tt 8192
#define EPSf 1e-5f
#define BAND 6e-3f       // fp64-rescue band for argmax ties

typedef __attribute__((ext_vector_type(8))) __bf16 bf16x8;
typedef __attribute__((ext_vector_type(4))) float f32x4;

#define GLOBAL_AS __attribute__((address_space(1)))
#define LDS_AS __attribute__((address_space(3)))

#define MAXTILES 137     // sum_p ceil(cnt_p/64) <= 8192/64 + 9
#define MAXT32   265     // sum_p ceil(cnt_p/32) <= 8192/32 + 9

__device__ __forceinline__ unsigned short bf16rn(float f) {
  unsigned int u = __float_as_uint(f);
  unsigned int r = (u + 0x7fffu + ((u >> 16) & 1u)) >> 16;
  return (unsigned short)r;
}

__device__ __forceinline__ void gload16(const void* g, void* l) {
  __builtin_amdgcn_global_load_lds((const GLOBAL_AS unsigned int*)g,
                                   (LDS_AS unsigned int*)l, 16, 0, 0);
}

// bijective XCD-chunked block swizzle (m204)
__device__ __forceinline__ int xcd_swz(int bx, int nwg) {
  const int q = nwg >> 3, r = nwg & 7;
  const int xcd = bx & 7, loc = bx >> 3;
  return (xcd < r ? xcd * (q + 1) : r * (q + 1) + (xcd - r) * q) + loc;
}

// swizzled LDS short-offset, BK=64 rows (8 x 16B slots/row)
#define KSW(r, sl) (((r) << 6) + ((((sl) ^ ((r) & 7))) << 3))

// ---------------------------------------------------------------- prep: mix -> bf16 (XCD-chunked) + weight cvt/T + zero counts
__global__ __launch_bounds__(256) void k_prep(const float* __restrict__ x,
    const float* __restrict__ mk, unsigned short* __restrict__ xh,
    const float* __restrict__ W1, const float* __restrict__ W2,
    const float* __restrict__ Wo1,
    unsigned short* __restrict__ W1t, unsigned short* __restrict__ W2t,
    unsigned short* __restrict__ Wo1t, int* __restrict__ counts) {
  const int bid = blockIdx.x;
  if (bid < Tt) {
    if (bid == 0 && threadIdx.x < 64) counts[threadIdx.x] = 0;
    const int t = xcd_swz(bid, Tt);
    const int s = t & (Ss - 1);
    const int d = threadIdx.x << 2;
    const float* xc = x + (size_t)t * Dd + d;
    float4 vb = *(const float4*)xc;
    float4 va = make_float4(0.f, 0.f, 0.f, 0.f);
    float4 vc = make_float4(0.f, 0.f, 0.f, 0.f);
    if (s > 0)      va = *(const float4*)(xc - Dd);
    if (s < Ss - 1) vc = *(const float4*)(xc + Dd);
    const float4 k0 = *(const float4*)(mk + d);
    const float4 k1 = *(const float4*)(mk + Dd + d);
    const float4 k2 = *(const float4*)(mk + 2 * Dd + d);
    float4 o;
    o.x = k0.x * va.x + k1.x * vb.x + k2.x * vc.x;
    o.y = k0.y * va.y + k1.y * vb.y + k2.y * vc.y;
    o.z = k0.z * va.z + k1.z * vb.z + k2.z * vc.z;
    o.w = k0.w * va.w + k1.w * vb.w + k2.w * vc.w;
    ushort4 h;
    h.x = bf16rn(o.x); h.y = bf16rn(o.y); h.z = bf16rn(o.z); h.w = bf16rn(o.w);
    *(ushort4*)(xh + (size_t)t * Dd + d) = h;
    return;
  }
  const int i = bid - Tt;
  const int z = i >> 8, rem = i & 255;
  const int bx = rem & 31, by = rem >> 5;
  const float* in; unsigned short* outp; int R, C, r0, c0;
  if (z < Pp)          { in = W1;  outp = W1t;  R = Dd;  C = DMm; r0 = bx * 32; c0 = by * 32; }
  else if (z < 2 * Pp) { in = W2;  outp = W2t;  R = DMm; C = Dd;  r0 = by * 32; c0 = bx * 32; }
  else                 { in = Wo1; outp = Wo1t; R = Dd;  C = DMm; r0 = bx * 32; c0 = by * 32; }
  const int zi = (z < Pp) ? z : ((z < 2 * Pp) ? z - Pp : 0);
  const size_t zo = (size_t)zi * R * C;
  __shared__ float tile[32][33];
  const int tr = threadIdx.x >> 3, tc = (threadIdx.x & 7) << 2;
  float4 v = *(const float4*)(in + zo + (size_t)(r0 + tr) * C + c0 + tc);
  tile[tr][tc] = v.x; tile[tr][tc + 1] = v.y; tile[tr][tc + 2] = v.z; tile[tr][tc + 3] = v.w;
  __syncthreads();
  ushort4 h;
  h.x = bf16rn(tile[tc + 0][tr]); h.y = bf16rn(tile[tc + 1][tr]);
  h.z = bf16rn(tile[tc + 2][tr]); h.w = bf16rn(tile[tc + 3][tr]);
  *(ushort4*)(outp + zo + (size_t)(c0 + tr) * R + r0 + tc) = h;
}

// ---------------------------------------------------------------- fused observer GEMM + tanh + partial scores
// 32 tokens x 128 cols per block; writes pscore[t][y][9] (no hidden buffer)
__global__ __launch_bounds__(256) void k_obs(
    const unsigned short* __restrict__ A,      // xm_h [Tt][Dd]
    const unsigned short* __restrict__ Bt,     // Wo1t [DMm][Dd]
    const float* __restrict__ bo1,
    const float* __restrict__ Wo2,             // [DMm][Pp]
    float* __restrict__ pscore) {              // [Tt][2][Pp]
  const int ti = xcd_swz(blockIdx.x, gridDim.x);
  const int tile0 = ti * 32;
  const int n0 = blockIdx.y * 128;
  __shared__ __align__(16) unsigned short As[2][32 * 64];
  __shared__ __align__(16) unsigned short Bs[2][128 * 64];
  __shared__ float sW[128 * Pp];
  __shared__ float part[2][32][Pp];
  const int tid = threadIdx.x;
  for (int l = tid; l < 128 * Pp; l += 256) sW[l] = Wo2[n0 * Pp + l];
  __syncthreads();
  const int w = tid >> 6, lane = tid & 63;
  const int fr = lane & 15, fs = lane >> 4;
  const int wr = w >> 1, wc = w & 1;
  const unsigned short* srcA;
  { const int r = tid >> 3, sl = (tid & 7) ^ (r & 7);
    srcA = A + (size_t)(tile0 + r) * Dd + sl * 8; }
  const unsigned short* srcB[4];
  #pragma unroll
  for (int i = 0; i < 4; ++i) {
    const int u = i * 256 + tid, r = u >> 3, sl = (u & 7) ^ (r & 7);
    srcB[i] = Bt + (size_t)(n0 + r) * Dd + sl * 8;
  }
  const int ldsW = w * 512;
  int aoff[2], boff[4][2];
  #pragma unroll
  for (int kk = 0; kk < 2; ++kk) aoff[kk] = KSW(wr * 16 + fr, kk * 4 + fs);
  #pragma unroll
  for (int n = 0; n < 4; ++n)
    #pragma unroll
    for (int kk = 0; kk < 2; ++kk)
      boff[n][kk] = KSW(wc * 64 + n * 16 + fr, kk * 4 + fs);

#define STAGE(b, kb) do { \
    gload16(srcA + (kb), &As[b][0] + ldsW); \
    gload16(srcB[0] + (kb), &Bs[b][0] + ldsW); \
    gload16(srcB[1] + (kb), &Bs[b][0] + 2048 + ldsW); \
    gload16(srcB[2] + (kb), &Bs[b][0] + 4096 + ldsW); \
    gload16(srcB[3] + (kb), &Bs[b][0] + 6144 + ldsW); \
  } while (0)

  f32x4 acc[4] = {};
  const int NS = Dd / 64;
  STAGE(0, 0);
  for (int s = 0; s < NS; ++s) {
    const int buf = s & 1;
    if (s + 1 < NS) {
      STAGE(buf ^ 1, (s + 1) * 64);
      asm volatile("s_waitcnt vmcnt(5)" ::: "memory");
    } else {
      asm volatile("s_waitcnt vmcnt(0)" ::: "memory");
    }
    __builtin_amdgcn_s_barrier();
    __builtin_amdgcn_sched_barrier(0);
    const unsigned short* Ab = &As[buf][0];
    const unsigned short* Bb_ = &Bs[buf][0];
    bf16x8 a[2], b[4][2];
    #pragma unroll
    for (int kk = 0; kk < 2; ++kk) a[kk] = *(const bf16x8*)&Ab[aoff[kk]];
    #pragma unroll
    for (int n = 0; n < 4; ++n)
      #pragma unroll
      for (int kk = 0; kk < 2; ++kk)
        b[n][kk] = *(const bf16x8*)&Bb_[boff[n][kk]];
    #pragma unroll
    for (int kk = 0; kk < 2; ++kk)
      #pragma unroll
      for (int n = 0; n < 4; ++n)
        acc[n] = __builtin_amdgcn_mfma_f32_16x16x32_bf16(a[kk], b[n][kk], acc[n], 0, 0, 0);
    __builtin_amdgcn_s_barrier();
  }
#undef STAGE

  // epilogue: tanh + contract with Wo2 slice -> per-row partial scores
  float ps[4][Pp] = {};
  #pragma unroll
  for (int n = 0; n < 4; ++n) {
    const int cl = wc * 64 + n * 16 + fr;
    const float bv = bo1[n0 + cl];
    #pragma unroll
    for (int j = 0; j < 4; ++j) {
      const float tv = tanhf(acc[n][j] + bv);
      #pragma unroll
      for (int p = 0; p < Pp; ++p) ps[j][p] += tv * sW[cl * Pp + p];
    }
  }
  #pragma unroll
  for (int off = 1; off < 16; off <<= 1)
    #pragma unroll
    for (int j = 0; j < 4; ++j)
      #pragma unroll
      for (int p = 0; p < Pp; ++p)
        ps[j][p] += __shfl_xor(ps[j][p], off);
  if (fr == 0) {
    #pragma unroll
    for (int j = 0; j < 4; ++j)
      #pragma unroll
      for (int p = 0; p < Pp; ++p)
        part[wc][wr * 16 + fs * 4 + j][p] = ps[j][p];
  }
  __syncthreads();
  for (int l = tid; l < 32 * Pp; l += 256) {
    const int r = l / Pp, p = l - r * Pp;
    pscore[(size_t)(tile0 + r) * (2 * Pp) + blockIdx.y * Pp + p] =
        part[0][r][p] + part[1][r][p];
  }
}

// ---------------------------------------------------------------- final scores + argmax + near-tie flag
__global__ __launch_bounds__(256) void k_amax(const float* __restrict__ pscore,
    const float* __restrict__ bo2,
    int* __restrict__ idx, int* __restrict__ nflag, int* __restrict__ flagged) {
  const int t = blockIdx.x * 256 + threadIdx.x;
  const float* pr = pscore + (size_t)t * (2 * Pp);
  float best = -1e30f, second = -1e30f;
  int bi = 0;
  #pragma unroll
  for (int p = 0; p < Pp; ++p) {
    const float sc = pr[p] + pr[Pp + p] + bo2[p];
    if (sc > best) { second = best; best = sc; bi = p; }
    else if (sc > second) second = sc;
  }
  idx[t] = bi;
  if (best - second < BAND) {
    const int pos = atomicAdd(nflag, 1);
    flagged[pos] = t;
  }
}

// ---------------------------------------------------------------- pipelined MFMA GEMM, TMx128 tile, BK=64, XCD-swizzled packed grid
// MODE 1: outh = bf16(acc+bias)   MODE 2: outf = acc+bias+resid
template<int KTOT, int NTOT, int MODE, int TM>
__global__ __launch_bounds__(256) void k_gemm(
    const unsigned short* __restrict__ A,
    const unsigned short* __restrict__ Bt,
    const float* __restrict__ bias,
    const float* __restrict__ resid,
    float* __restrict__ outf, unsigned short* __restrict__ outh,
    const int* __restrict__ counts, const int* __restrict__ tokenlist) {
  constexpr int MM = TM / 32;
  int p = 0, ti = xcd_swz(blockIdx.x, gridDim.x), cnt = Tt;
  for (p = 0; p < Pp; ++p) {
    cnt = counts[p];
    const int nt = (cnt + TM - 1) / TM;
    if (ti < nt) break;
    ti -= nt;
  }
  if (p == Pp) return;
  const int tile0 = ti * TM;
  __shared__ int tl[TM];
  __shared__ __align__(16) unsigned short As[2][TM * 64];
  __shared__ __align__(16) unsigned short Bs[2][128 * 64];
  const int tid = threadIdx.x;
  if (tid < TM) {
    const int li = tile0 + tid;
    tl[tid] = (li < cnt) ? tokenlist[p * Tt + li] : tokenlist[p * Tt];
  }
  __syncthreads();
  const int w = tid >> 6, lane = tid & 63;
  const int fr = lane & 15, fs = lane >> 4;
  const int wr = w >> 1, wc = w & 1;
  const int n0 = blockIdx.y * 128;
  const unsigned short* Bp0 = Bt + (size_t)p * NTOT * KTOT + (size_t)n0 * KTOT;
  const unsigned short* srcA[MM];
  #pragma unroll
  for (int i = 0; i < MM; ++i) {
    const int u = i * 256 + tid, r = u >> 3, sl = (u & 7) ^ (r & 7);
    srcA[i] = A + (size_t)tl[r] * KTOT + sl * 8;
  }
  const unsigned short* srcB[4];
  #pragma unroll
  for (int i = 0; i < 4; ++i) {
    const int u = i * 256 + tid, r = u >> 3, sl = (u & 7) ^ (r & 7);
    srcB[i] = Bp0 + (size_t)r * KTOT + sl * 8;
  }
  const int ldsW = w * 512;
  int aoff[MM][2], boff[4][2];
  #pragma unroll
  for (int m = 0; m < MM; ++m)
    #pragma unroll
    for (int kk = 0; kk < 2; ++kk)
      aoff[m][kk] = KSW(wr * (TM / 2) + m * 16 + fr, kk * 4 + fs);
  #pragma unroll
  for (int n = 0; n < 4; ++n)
    #pragma unroll
    for (int kk = 0; kk < 2; ++kk)
      boff[n][kk] = KSW(wc * 64 + n * 16 + fr, kk * 4 + fs);

#define STAGE(b, kb) do { \
    _Pragma("unroll") \
    for (int i = 0; i < MM; ++i) \
      gload16(srcA[i] + (kb), &As[b][0] + i * 2048 + ldsW); \
    gload16(srcB[0] + (kb), &Bs[b][0] + ldsW); \
    gload16(srcB[1] + (kb), &Bs[b][0] + 2048 + ldsW); \
    gload16(srcB[2] + (kb), &Bs[b][0] + 4096 + ldsW); \
    gload16(srcB[3] + (kb), &Bs[b][0] + 6144 + ldsW); \
  } while (0)

  f32x4 acc[MM][4] = {};
  const int NS = KTOT / 64;
  STAGE(0, 0);
  for (int s = 0; s < NS; ++s) {
    const int buf = s & 1;
    if (s + 1 < NS) {
      STAGE(buf ^ 1, (s + 1) * 64);
      if (TM == 64) asm volatile("s_waitcnt vmcnt(6)" ::: "memory");
      else          asm volatile("s_waitcnt vmcnt(5)" ::: "memory");
    } else {
      asm volatile("s_waitcnt vmcnt(0)" ::: "memory");
    }
    __builtin_amdgcn_s_barrier();
    __builtin_amdgcn_sched_barrier(0);
    const unsigned short* Ab = &As[buf][0];
    const unsigned short* Bb_ = &Bs[buf][0];
    bf16x8 a[MM][2], b[4][2];
    #pragma unroll
    for (int m = 0; m < MM; ++m)
      #pragma unroll
      for (int kk = 0; kk < 2; ++kk)
        a[m][kk] = *(const bf16x8*)&Ab[aoff[m][kk]];
    #pragma unroll
    for (int n = 0; n < 4; ++n)
      #pragma unroll
      for (int kk = 0; kk < 2; ++kk)
        b[n][kk] = *(const bf16x8*)&Bb_[boff[n][kk]];
    #pragma unroll
    for (int kk = 0; kk < 2; ++kk)
      #pragma unroll
      for (int m = 0; m < MM; ++m)
        #pragma unroll
        for (int n = 0; n < 4; ++n)
          acc[m][n] = __builtin_amdgcn_mfma_f32_16x16x32_bf16(a[m][kk], b[n][kk], acc[m][n], 0, 0, 0);
    __builtin_amdgcn_s_barrier();
  }
#undef STAGE

  const float* bias_z = bias + (size_t)p * NTOT;
  #pragma unroll
  for (int m = 0; m < MM; ++m) {
    #pragma unroll
    for (int j = 0; j < 4; ++j) {
      const int rr = wr * (TM / 2) + m * 16 + fs * 4 + j;
      const int li = tile0 + rr;
      if (li >= cnt) continue;
      const int t = tl[rr];
      #pragma unroll
      for (int n = 0; n < 4; ++n) {
        const int c = n0 + wc * 64 + n * 16 + fr;
        const float v = acc[m][n][j] + bias_z[c];
        if (MODE == 1) outh[(size_t)t * NTOT + c] = bf16rn(v);
        else           outf[(size_t)t * NTOT + c] = v + resid[(size_t)t * NTOT + c];
      }
    }
  }
}

// ---------------------------------------------------------------- fp64 rescue (parallelized)
__global__ __launch_bounds__(256) void k_rescue(const float* __restrict__ x,
    const float* __restrict__ mk,
    const float* __restrict__ Wo1, const float* __restrict__ bo1,
    const float* __restrict__ Wo2, const float* __restrict__ bo2,
    const int* __restrict__ nflag, const int* __restrict__ flagged,
    int* __restrict__ idx) {
  __shared__ double sx[Dd];
  __shared__ double th[DMm];
  __shared__ double red[4][12];
  const int nf = *nflag;
  const int tid = threadIdx.x;
  const int wv = tid >> 6, ln = tid & 63;
  for (int f = blockIdx.x; f < nf; f += gridDim.x) {
    const int t = flagged[f];
    const int s = t & (Ss - 1);
    for (int l = tid; l < Dd; l += 256) {
      const double xa = (s > 0)      ? (double)x[(size_t)(t - 1) * Dd + l] : 0.0;
      const double xb =                (double)x[(size_t)t * Dd + l];
      const double xc = (s < Ss - 1) ? (double)x[(size_t)(t + 1) * Dd + l] : 0.0;
      sx[l] = (double)mk[l] * xa + (double)mk[Dd + l] * xb + (double)mk[2 * Dd + l] * xc;
    }
    __syncthreads();
    {
      double a0 = 0, a1 = 0, a2 = 0, a3 = 0;
      const float* wcol = Wo1 + tid;
      for (int d = 0; d < Dd; d += 4) {
        a0 += sx[d + 0] * (double)wcol[(size_t)(d + 0) * DMm];
        a1 += sx[d + 1] * (double)wcol[(size_t)(d + 1) * DMm];
        a2 += sx[d + 2] * (double)wcol[(size_t)(d + 2) * DMm];
        a3 += sx[d + 3] * (double)wcol[(size_t)(d + 3) * DMm];
      }
      th[tid] = tanh(((a0 + a1) + (a2 + a3)) + (double)bo1[tid]);
    }
    __syncthreads();
    double pr[Pp];
    const double tv = th[tid];
    #pragma unroll
    for (int p = 0; p < Pp; ++p) pr[p] = tv * (double)Wo2[tid * Pp + p];
    #pragma unroll
    for (int off = 32; off > 0; off >>= 1)
      #pragma unroll
      for (int p = 0; p < Pp; ++p) pr[p] += __shfl_xor(pr[p], off);
    if (ln == 0) {
      #pragma unroll
      for (int p = 0; p < Pp; ++p) red[wv][p] = pr[p];
    }
    __syncthreads();
    if (tid == 0) {
      double best = -1e300; int bi = 0;
      #pragma unroll
      for (int p = 0; p < Pp; ++p) {
        const double sv = red[0][p] + red[1][p] + red[2][p] + red[3][p] + (double)bo2[p];
        if (sv > best) { best = sv; bi = p; }
      }
      idx[t] = bi;
    }
    __syncthreads();
  }
}

// ---------------------------------------------------------------- group tokens by path (LDS histogram)
__global__ __launch_bounds__(256) void k_scatter(const int* __restrict__ idx,
    int* __restrict__ counts, int* __restrict__ tokenlist) {
  __shared__ int lcnt[Pp], lbase[Pp];
  const int tid = threadIdx.x;
  if (tid < Pp) lcnt[tid] = 0;
  __syncthreads();
  const int t = blockIdx.x * 256 + tid;
  const int p = idx[t];
  const int slot = atomicAdd(&lcnt[p], 1);
  __syncthreads();
  if (tid < Pp) lbase[tid] = atomicAdd(&counts[tid], lcnt[tid]);
  __syncthreads();
  tokenlist[p * Tt + lbase[p] + slot] = t;
}

// ---------------------------------------------------------------- in-place LayerNorm
__global__ __launch_bounds__(256) void k_ln(float* __restrict__ y,
    const float* __restrict__ gamma, const float* __restrict__ beta) {
  const int t = blockIdx.x;
  const int d = threadIdx.x << 2;
  float* row = y + (size_t)t * Dd;
  float4 v = *(float4*)(row + d);
  float s = v.x + v.y + v.z + v.w;
  float q = v.x * v.x + v.y * v.y + v.z * v.z + v.w * v.w;
  #pragma unroll
  for (int off = 32; off > 0; off >>= 1) {
    s += __shfl_xor(s, off);
    q += __shfl_xor(q, off);
  }
  __shared__ float ssum[4], sqq[4];
  const int wave = threadIdx.x >> 6, lane = threadIdx.x & 63;
  if (lane == 0) { ssum[wave] = s; sqq[wave] = q; }
  __syncthreads();
  s = ssum[0] + ssum[1] + ssum[2] + ssum[3];
  q = sqq[0] + sqq[1] + sqq[2] + sqq[3];
  const float mu = s * (1.f / Dd);
  const float var = q * (1.f / Dd) - mu * mu;
  const float inv = rsqrtf(var + EPSf);
  const float4 g = *(const float4*)(gamma + d);
  const float4 bt = *(const float4*)(beta + d);
  float4 o;
  o.x = (v.x - mu) * inv * g.x + bt.x;
  o.y = (v.y - mu) * inv * g.y + bt.y;
  o.z = (v.z - mu) * inv * g.z + bt.z;
  o.w = (v.w - mu) * inv * g.w + bt.w;
  *(float4*)(row + d) = o;
}

// ----------------------------------------------------------------
extern "C" void kernel_launch(void* const* d_in, const int* in_sizes, int n_in,
                              void* d_out, int out_size, void* d_ws, size_t ws_size,
                              hipStream_t stream) {
  (void)in_sizes; (void)n_in; (void)out_size; (void)ws_size;
  const float* x     = (const float*)d_in[0];
  const float* mk    = (const float*)d_in[1];
  const float* W1    = (const float*)d_in[2];
  const float* b1    = (const float*)d_in[3];
  const float* W2    = (const float*)d_in[4];
  const float* b2    = (const float*)d_in[5];
  const float* Wo1   = (const float*)d_in[6];
  const float* bo1   = (const float*)d_in[7];
  const float* Wo2   = (const float*)d_in[8];
  const float* bo2   = (const float*)d_in[9];
  const float* gamma = (const float*)d_in[10];
  const float* beta  = (const float*)d_in[11];
  float* out = (float*)d_out;

  size_t off = 0;
  auto alloc = [&](size_t bytes) -> void* {
    void* p = (char*)d_ws + off;
    off += (bytes + 255) & ~(size_t)255;
    return p;
  };
  unsigned short* xm_h   = (unsigned short*)alloc((size_t)Tt * Dd * 2);
  unsigned short* h1     = (unsigned short*)alloc((size_t)Tt * DMm * 2);
  float*          pscore = (float*)alloc((size_t)Tt * 2 * Pp * 4);
  unsigned short* W1t    = (unsigned short*)alloc((size_t)Pp * Dd * DMm * 2);
  unsigned short* W2t    = (unsigned short*)alloc((size_t)Pp * DMm * Dd * 2);
  unsigned short* Wo1t   = (unsigned short*)alloc((size_t)Dd * DMm * 2);
  int* idx      = (int*)alloc(Tt * 4);
  int* counts   = (int*)alloc(64 * 4);
  int* nflag    = counts + 16;
  int* flagged  = (int*)alloc(Tt * 4);
  int* tokenlist = (int*)alloc((size_t)Pp * Tt * 4);

  k_prep<<<Tt + (2 * Pp + 1) * 256, 256, 0, stream>>>(
      x, mk, xm_h, W1, W2, Wo1, W1t, W2t, Wo1t, counts);

  k_obs<<<dim3(Tt / 32, DMm / 128), 256, 0, stream>>>(
      xm_h, Wo1t, bo1, Wo2, pscore);
  k_amax<<<Tt / 256, 256, 0, stream>>>(pscore, bo2, idx, nflag, flagged);
  k_rescue<<<256, 256, 0, stream>>>(x, mk, Wo1, bo1, Wo2, bo2, nflag, flagged, idx);
  k_scatter<<<Tt / 256, 256, 0, stream>>>(idx, counts, tokenlist);

  k_gemm<Dd, DMm, 1, 32><<<dim3(MAXT32, DMm / 128), 256, 0, stream>>>(
      xm_h, W1t, b1, nullptr, nullptr, h1, counts, tokenlist);
  k_gemm<DMm, Dd, 2, 64><<<dim3(MAXTILES, Dd / 128), 256, 0, stream>>>(
      h1, W2t, b2, x, out, nullptr, counts, tokenlist);
  k_ln<<<Tt, 256, 0, stream>>>(out, gamma, beta);
}

// Round 15
// 123.434 us; speedup vs baseline: 1.3815x; 1.0354x over previous
//
#include <hip/hip_runtime.h>
#include <math.h>

#define Ss 2048
#define Dd 1024
#define Pp 9
#define DMm 256
#define Tt 8192
#define EPSf 1e-5f
#define BAND 6e-3f       // fp64-rescue band for argmax ties

typedef __attribute__((ext_vector_type(8))) __bf16 bf16x8;
typedef __attribute__((ext_vector_type(4))) float f32x4;

#define GLOBAL_AS __attribute__((address_space(1)))
#define LDS_AS __attribute__((address_space(3)))

#define MAXTILES 137     // sum_p ceil(cnt_p/64) <= 8192/64 + 9
#define MAXT32   265     // sum_p ceil(cnt_p/32) <= 8192/32 + 9

__device__ __forceinline__ unsigned short bf16rn(float f) {
  unsigned int u = __float_as_uint(f);
  unsigned int r = (u + 0x7fffu + ((u >> 16) & 1u)) >> 16;
  return (unsigned short)r;
}

__device__ __forceinline__ float b2f(unsigned short h) {
  return __uint_as_float((unsigned int)h << 16);
}

__device__ __forceinline__ void gload16(const void* g, void* l) {
  __builtin_amdgcn_global_load_lds((const GLOBAL_AS unsigned int*)g,
                                   (LDS_AS unsigned int*)l, 16, 0, 0);
}

// bijective XCD-chunked block swizzle (m204)
__device__ __forceinline__ int xcd_swz(int bx, int nwg) {
  const int q = nwg >> 3, r = nwg & 7;
  const int xcd = bx & 7, loc = bx >> 3;
  return (xcd < r ? xcd * (q + 1) : r * (q + 1) + (xcd - r) * q) + loc;
}

// swizzled LDS short-offset, BK=64 rows (8 x 16B slots/row)
#define KSW(r, sl) (((r) << 6) + ((((sl) ^ ((r) & 7))) << 3))

// ---------------------------------------------------------------- prep: mix -> bf16 (XCD-chunked) + weight cvt/T + zero counts
__global__ __launch_bounds__(256) void k_prep(const float* __restrict__ x,
    const float* __restrict__ mk, unsigned short* __restrict__ xh,
    const float* __restrict__ W1, const float* __restrict__ W2,
    const float* __restrict__ Wo1,
    unsigned short* __restrict__ W1t, unsigned short* __restrict__ W2t,
    unsigned short* __restrict__ Wo1t, int* __restrict__ counts) {
  const int bid = blockIdx.x;
  if (bid < Tt) {
    if (bid == 0 && threadIdx.x < 64) counts[threadIdx.x] = 0;
    const int t = xcd_swz(bid, Tt);
    const int s = t & (Ss - 1);
    const int d = threadIdx.x << 2;
    const float* xc = x + (size_t)t * Dd + d;
    float4 vb = *(const float4*)xc;
    float4 va = make_float4(0.f, 0.f, 0.f, 0.f);
    float4 vc = make_float4(0.f, 0.f, 0.f, 0.f);
    if (s > 0)      va = *(const float4*)(xc - Dd);
    if (s < Ss - 1) vc = *(const float4*)(xc + Dd);
    const float4 k0 = *(const float4*)(mk + d);
    const float4 k1 = *(const float4*)(mk + Dd + d);
    const float4 k2 = *(const float4*)(mk + 2 * Dd + d);
    float4 o;
    o.x = k0.x * va.x + k1.x * vb.x + k2.x * vc.x;
    o.y = k0.y * va.y + k1.y * vb.y + k2.y * vc.y;
    o.z = k0.z * va.z + k1.z * vb.z + k2.z * vc.z;
    o.w = k0.w * va.w + k1.w * vb.w + k2.w * vc.w;
    ushort4 h;
    h.x = bf16rn(o.x); h.y = bf16rn(o.y); h.z = bf16rn(o.z); h.w = bf16rn(o.w);
    *(ushort4*)(xh + (size_t)t * Dd + d) = h;
    return;
  }
  const int i = bid - Tt;
  const int z = i >> 8, rem = i & 255;
  const int bx = rem & 31, by = rem >> 5;
  const float* in; unsigned short* outp; int R, C, r0, c0;
  if (z < Pp)          { in = W1;  outp = W1t;  R = Dd;  C = DMm; r0 = bx * 32; c0 = by * 32; }
  else if (z < 2 * Pp) { in = W2;  outp = W2t;  R = DMm; C = Dd;  r0 = by * 32; c0 = bx * 32; }
  else                 { in = Wo1; outp = Wo1t; R = Dd;  C = DMm; r0 = bx * 32; c0 = by * 32; }
  const int zi = (z < Pp) ? z : ((z < 2 * Pp) ? z - Pp : 0);
  const size_t zo = (size_t)zi * R * C;
  __shared__ float tile[32][33];
  const int tr = threadIdx.x >> 3, tc = (threadIdx.x & 7) << 2;
  float4 v = *(const float4*)(in + zo + (size_t)(r0 + tr) * C + c0 + tc);
  tile[tr][tc] = v.x; tile[tr][tc + 1] = v.y; tile[tr][tc + 2] = v.z; tile[tr][tc + 3] = v.w;
  __syncthreads();
  ushort4 h;
  h.x = bf16rn(tile[tc + 0][tr]); h.y = bf16rn(tile[tc + 1][tr]);
  h.z = bf16rn(tile[tc + 2][tr]); h.w = bf16rn(tile[tc + 3][tr]);
  *(ushort4*)(outp + zo + (size_t)(c0 + tr) * R + r0 + tc) = h;
}

// ---------------------------------------------------------------- fused observer GEMM + tanh + partial scores
__global__ __launch_bounds__(256) void k_obs(
    const unsigned short* __restrict__ A,      // xm_h [Tt][Dd]
    const unsigned short* __restrict__ Bt,     // Wo1t [DMm][Dd]
    const float* __restrict__ bo1,
    const float* __restrict__ Wo2,             // [DMm][Pp]
    float* __restrict__ pscore) {              // [Tt][2][Pp]
  const int ti = xcd_swz(blockIdx.x, gridDim.x);
  const int tile0 = ti * 32;
  const int n0 = blockIdx.y * 128;
  __shared__ __align__(16) unsigned short As[2][32 * 64];
  __shared__ __align__(16) unsigned short Bs[2][128 * 64];
  __shared__ float sW[128 * Pp];
  __shared__ float part[2][32][Pp];
  const int tid = threadIdx.x;
  for (int l = tid; l < 128 * Pp; l += 256) sW[l] = Wo2[n0 * Pp + l];
  __syncthreads();
  const int w = tid >> 6, lane = tid & 63;
  const int fr = lane & 15, fs = lane >> 4;
  const int wr = w >> 1, wc = w & 1;
  const unsigned short* srcA;
  { const int r = tid >> 3, sl = (tid & 7) ^ (r & 7);
    srcA = A + (size_t)(tile0 + r) * Dd + sl * 8; }
  const unsigned short* srcB[4];
  #pragma unroll
  for (int i = 0; i < 4; ++i) {
    const int u = i * 256 + tid, r = u >> 3, sl = (u & 7) ^ (r & 7);
    srcB[i] = Bt + (size_t)(n0 + r) * Dd + sl * 8;
  }
  const int ldsW = w * 512;
  int aoff[2], boff[4][2];
  #pragma unroll
  for (int kk = 0; kk < 2; ++kk) aoff[kk] = KSW(wr * 16 + fr, kk * 4 + fs);
  #pragma unroll
  for (int n = 0; n < 4; ++n)
    #pragma unroll
    for (int kk = 0; kk < 2; ++kk)
      boff[n][kk] = KSW(wc * 64 + n * 16 + fr, kk * 4 + fs);

#define STAGE(b, kb) do { \
    gload16(srcA + (kb), &As[b][0] + ldsW); \
    gload16(srcB[0] + (kb), &Bs[b][0] + ldsW); \
    gload16(srcB[1] + (kb), &Bs[b][0] + 2048 + ldsW); \
    gload16(srcB[2] + (kb), &Bs[b][0] + 4096 + ldsW); \
    gload16(srcB[3] + (kb), &Bs[b][0] + 6144 + ldsW); \
  } while (0)

  f32x4 acc[4] = {};
  const int NS = Dd / 64;
  STAGE(0, 0);
  for (int s = 0; s < NS; ++s) {
    const int buf = s & 1;
    if (s + 1 < NS) {
      STAGE(buf ^ 1, (s + 1) * 64);
      asm volatile("s_waitcnt vmcnt(5)" ::: "memory");
    } else {
      asm volatile("s_waitcnt vmcnt(0)" ::: "memory");
    }
    __builtin_amdgcn_s_barrier();
    __builtin_amdgcn_sched_barrier(0);
    const unsigned short* Ab = &As[buf][0];
    const unsigned short* Bb_ = &Bs[buf][0];
    bf16x8 a[2], b[4][2];
    #pragma unroll
    for (int kk = 0; kk < 2; ++kk) a[kk] = *(const bf16x8*)&Ab[aoff[kk]];
    #pragma unroll
    for (int n = 0; n < 4; ++n)
      #pragma unroll
      for (int kk = 0; kk < 2; ++kk)
        b[n][kk] = *(const bf16x8*)&Bb_[boff[n][kk]];
    #pragma unroll
    for (int kk = 0; kk < 2; ++kk)
      #pragma unroll
      for (int n = 0; n < 4; ++n)
        acc[n] = __builtin_amdgcn_mfma_f32_16x16x32_bf16(a[kk], b[n][kk], acc[n], 0, 0, 0);
    __builtin_amdgcn_s_barrier();
  }
#undef STAGE

  float ps[4][Pp] = {};
  #pragma unroll
  for (int n = 0; n < 4; ++n) {
    const int cl = wc * 64 + n * 16 + fr;
    const float bv = bo1[n0 + cl];
    #pragma unroll
    for (int j = 0; j < 4; ++j) {
      const float tv = tanhf(acc[n][j] + bv);
      #pragma unroll
      for (int p = 0; p < Pp; ++p) ps[j][p] += tv * sW[cl * Pp + p];
    }
  }
  #pragma unroll
  for (int off = 1; off < 16; off <<= 1)
    #pragma unroll
    for (int j = 0; j < 4; ++j)
      #pragma unroll
      for (int p = 0; p < Pp; ++p)
        ps[j][p] += __shfl_xor(ps[j][p], off);
  if (fr == 0) {
    #pragma unroll
    for (int j = 0; j < 4; ++j)
      #pragma unroll
      for (int p = 0; p < Pp; ++p)
        part[wc][wr * 16 + fs * 4 + j][p] = ps[j][p];
  }
  __syncthreads();
  for (int l = tid; l < 32 * Pp; l += 256) {
    const int r = l / Pp, p = l - r * Pp;
    pscore[(size_t)(tile0 + r) * (2 * Pp) + blockIdx.y * Pp + p] =
        part[0][r][p] + part[1][r][p];
  }
}

// ---------------------------------------------------------------- scores + argmax + flag + scatter (256 tokens/block)
__global__ __launch_bounds__(256) void k_amax(const float* __restrict__ pscore,
    const float* __restrict__ bo2,
    int* __restrict__ nflag, int* __restrict__ flagged,
    int* __restrict__ counts, int* __restrict__ tokenlist) {
  __shared__ int lcnt[Pp], lbase[Pp];
  const int tid = threadIdx.x;
  if (tid < Pp) lcnt[tid] = 0;
  __syncthreads();
  const int t = blockIdx.x * 256 + tid;
  const float* pr = pscore + (size_t)t * (2 * Pp);
  float best = -1e30f, second = -1e30f;
  int bi = 0;
  #pragma unroll
  for (int p = 0; p < Pp; ++p) {
    const float sc = pr[p] + pr[Pp + p] + bo2[p];
    if (sc > best) { second = best; best = sc; bi = p; }
    else if (sc > second) second = sc;
  }
  int slot = -1;
  if (best - second < BAND) {
    flagged[atomicAdd(nflag, 1)] = t;   // rescue will scatter this token
  } else {
    slot = atomicAdd(&lcnt[bi], 1);
  }
  __syncthreads();
  if (tid < Pp) lbase[tid] = atomicAdd(&counts[tid], lcnt[tid]);
  __syncthreads();
  if (slot >= 0) tokenlist[bi * Tt + lbase[bi] + slot] = t;
}

// ---------------------------------------------------------------- pipelined MFMA GEMM, TMx128 tile, BK=64, XCD-swizzled packed grid
// MODE 1: outh = bf16(acc+bias)   MODE 2: outh = bf16(acc+bias+resid)
template<int KTOT, int NTOT, int MODE, int TM>
__global__ __launch_bounds__(256) void k_gemm(
    const unsigned short* __restrict__ A,
    const unsigned short* __restrict__ Bt,
    const float* __restrict__ bias,
    const float* __restrict__ resid,
    unsigned short* __restrict__ outh,
    const int* __restrict__ counts, const int* __restrict__ tokenlist) {
  constexpr int MM = TM / 32;
  int p = 0, ti = xcd_swz(blockIdx.x, gridDim.x), cnt = Tt;
  for (p = 0; p < Pp; ++p) {
    cnt = counts[p];
    const int nt = (cnt + TM - 1) / TM;
    if (ti < nt) break;
    ti -= nt;
  }
  if (p == Pp) return;
  const int tile0 = ti * TM;
  __shared__ int tl[TM];
  __shared__ __align__(16) unsigned short As[2][TM * 64];
  __shared__ __align__(16) unsigned short Bs[2][128 * 64];
  const int tid = threadIdx.x;
  if (tid < TM) {
    const int li = tile0 + tid;
    tl[tid] = (li < cnt) ? tokenlist[p * Tt + li] : tokenlist[p * Tt];
  }
  __syncthreads();
  const int w = tid >> 6, lane = tid & 63;
  const int fr = lane & 15, fs = lane >> 4;
  const int wr = w >> 1, wc = w & 1;
  const int n0 = blockIdx.y * 128;
  const unsigned short* Bp0 = Bt + (size_t)p * NTOT * KTOT + (size_t)n0 * KTOT;
  const unsigned short* srcA[MM];
  #pragma unroll
  for (int i = 0; i < MM; ++i) {
    const int u = i * 256 + tid, r = u >> 3, sl = (u & 7) ^ (r & 7);
    srcA[i] = A + (size_t)tl[r] * KTOT + sl * 8;
  }
  const unsigned short* srcB[4];
  #pragma unroll
  for (int i = 0; i < 4; ++i) {
    const int u = i * 256 + tid, r = u >> 3, sl = (u & 7) ^ (r & 7);
    srcB[i] = Bp0 + (size_t)r * KTOT + sl * 8;
  }
  const int ldsW = w * 512;
  int aoff[MM][2], boff[4][2];
  #pragma unroll
  for (int m = 0; m < MM; ++m)
    #pragma unroll
    for (int kk = 0; kk < 2; ++kk)
      aoff[m][kk] = KSW(wr * (TM / 2) + m * 16 + fr, kk * 4 + fs);
  #pragma unroll
  for (int n = 0; n < 4; ++n)
    #pragma unroll
    for (int kk = 0; kk < 2; ++kk)
      boff[n][kk] = KSW(wc * 64 + n * 16 + fr, kk * 4 + fs);

#define STAGE(b, kb) do { \
    _Pragma("unroll") \
    for (int i = 0; i < MM; ++i) \
      gload16(srcA[i] + (kb), &As[b][0] + i * 2048 + ldsW); \
    gload16(srcB[0] + (kb), &Bs[b][0] + ldsW); \
    gload16(srcB[1] + (kb), &Bs[b][0] + 2048 + ldsW); \
    gload16(srcB[2] + (kb), &Bs[b][0] + 4096 + ldsW); \
    gload16(srcB[3] + (kb), &Bs[b][0] + 6144 + ldsW); \
  } while (0)

  f32x4 acc[MM][4] = {};
  const int NS = KTOT / 64;
  STAGE(0, 0);
  for (int s = 0; s < NS; ++s) {
    const int buf = s & 1;
    if (s + 1 < NS) {
      STAGE(buf ^ 1, (s + 1) * 64);
      if (TM == 64) asm volatile("s_waitcnt vmcnt(6)" ::: "memory");
      else          asm volatile("s_waitcnt vmcnt(5)" ::: "memory");
    } else {
      asm volatile("s_waitcnt vmcnt(0)" ::: "memory");
    }
    __builtin_amdgcn_s_barrier();
    __builtin_amdgcn_sched_barrier(0);
    const unsigned short* Ab = &As[buf][0];
    const unsigned short* Bb_ = &Bs[buf][0];
    bf16x8 a[MM][2], b[4][2];
    #pragma unroll
    for (int m = 0; m < MM; ++m)
      #pragma unroll
      for (int kk = 0; kk < 2; ++kk)
        a[m][kk] = *(const bf16x8*)&Ab[aoff[m][kk]];
    #pragma unroll
    for (int n = 0; n < 4; ++n)
      #pragma unroll
      for (int kk = 0; kk < 2; ++kk)
        b[n][kk] = *(const bf16x8*)&Bb_[boff[n][kk]];
    #pragma unroll
    for (int kk = 0; kk < 2; ++kk)
      #pragma unroll
      for (int m = 0; m < MM; ++m)
        #pragma unroll
        for (int n = 0; n < 4; ++n)
          acc[m][n] = __builtin_amdgcn_mfma_f32_16x16x32_bf16(a[m][kk], b[n][kk], acc[m][n], 0, 0, 0);
    __builtin_amdgcn_s_barrier();
  }
#undef STAGE

  const float* bias_z = bias + (size_t)p * NTOT;
  #pragma unroll
  for (int m = 0; m < MM; ++m) {
    #pragma unroll
    for (int j = 0; j < 4; ++j) {
      const int rr = wr * (TM / 2) + m * 16 + fs * 4 + j;
      const int li = tile0 + rr;
      if (li >= cnt) continue;
      const int t = tl[rr];
      #pragma unroll
      for (int n = 0; n < 4; ++n) {
        const int c = n0 + wc * 64 + n * 16 + fr;
        float v = acc[m][n][j] + bias_z[c];
        if (MODE == 2) v += resid[(size_t)t * NTOT + c];
        outh[(size_t)t * NTOT + c] = bf16rn(v);
      }
    }
  }
}

// ---------------------------------------------------------------- fp64 rescue (+ scatter of flagged tokens)
__global__ __launch_bounds__(256) void k_rescue(const float* __restrict__ x,
    const float* __restrict__ mk,
    const float* __restrict__ Wo1, const float* __restrict__ bo1,
    const float* __restrict__ Wo2, const float* __restrict__ bo2,
    const int* __restrict__ nflag, const int* __restrict__ flagged,
    int* __restrict__ counts, int* __restrict__ tokenlist) {
  __shared__ double sx[Dd];
  __shared__ double th[DMm];
  __shared__ double red[4][12];
  const int nf = *nflag;
  const int tid = threadIdx.x;
  const int wv = tid >> 6, ln = tid & 63;
  for (int f = blockIdx.x; f < nf; f += gridDim.x) {
    const int t = flagged[f];
    const int s = t & (Ss - 1);
    for (int l = tid; l < Dd; l += 256) {
      const double xa = (s > 0)      ? (double)x[(size_t)(t - 1) * Dd + l] : 0.0;
      const double xb =                (double)x[(size_t)t * Dd + l];
      const double xc = (s < Ss - 1) ? (double)x[(size_t)(t + 1) * Dd + l] : 0.0;
      sx[l] = (double)mk[l] * xa + (double)mk[Dd + l] * xb + (double)mk[2 * Dd + l] * xc;
    }
    __syncthreads();
    {
      double a0 = 0, a1 = 0, a2 = 0, a3 = 0;
      const float* wcol = Wo1 + tid;
      for (int d = 0; d < Dd; d += 4) {
        a0 += sx[d + 0] * (double)wcol[(size_t)(d + 0) * DMm];
        a1 += sx[d + 1] * (double)wcol[(size_t)(d + 1) * DMm];
        a2 += sx[d + 2] * (double)wcol[(size_t)(d + 2) * DMm];
        a3 += sx[d + 3] * (double)wcol[(size_t)(d + 3) * DMm];
      }
      th[tid] = tanh(((a0 + a1) + (a2 + a3)) + (double)bo1[tid]);
    }
    __syncthreads();
    double pr[Pp];
    const double tv = th[tid];
    #pragma unroll
    for (int p = 0; p < Pp; ++p) pr[p] = tv * (double)Wo2[tid * Pp + p];
    #pragma unroll
    for (int off = 32; off > 0; off >>= 1)
      #pragma unroll
      for (int p = 0; p < Pp; ++p) pr[p] += __shfl_xor(pr[p], off);
    if (ln == 0) {
      #pragma unroll
      for (int p = 0; p < Pp; ++p) red[wv][p] = pr[p];
    }
    __syncthreads();
    if (tid == 0) {
      double best = -1e300; int bi = 0;
      #pragma unroll
      for (int p = 0; p < Pp; ++p) {
        const double sv = red[0][p] + red[1][p] + red[2][p] + red[3][p] + (double)bo2[p];
        if (sv > best) { best = sv; bi = p; }
      }
      const int pos = atomicAdd(&counts[bi], 1);
      tokenlist[bi * Tt + pos] = t;
    }
    __syncthreads();
  }
}

// ---------------------------------------------------------------- LayerNorm: bf16 pre -> fp32 out
__global__ __launch_bounds__(256) void k_ln(const unsigned short* __restrict__ pre,
    float* __restrict__ out,
    const float* __restrict__ gamma, const float* __restrict__ beta) {
  const int t = blockIdx.x;
  const int d = threadIdx.x << 2;
  const ushort4 hv = *(const ushort4*)(pre + (size_t)t * Dd + d);
  float4 v;
  v.x = b2f(hv.x); v.y = b2f(hv.y); v.z = b2f(hv.z); v.w = b2f(hv.w);
  float s = v.x + v.y + v.z + v.w;
  float q = v.x * v.x + v.y * v.y + v.z * v.z + v.w * v.w;
  #pragma unroll
  for (int off = 32; off > 0; off >>= 1) {
    s += __shfl_xor(s, off);
    q += __shfl_xor(q, off);
  }
  __shared__ float ssum[4], sqq[4];
  const int wave = threadIdx.x >> 6, lane = threadIdx.x & 63;
  if (lane == 0) { ssum[wave] = s; sqq[wave] = q; }
  __syncthreads();
  s = ssum[0] + ssum[1] + ssum[2] + ssum[3];
  q = sqq[0] + sqq[1] + sqq[2] + sqq[3];
  const float mu = s * (1.f / Dd);
  const float var = q * (1.f / Dd) - mu * mu;
  const float inv = rsqrtf(var + EPSf);
  const float4 g = *(const float4*)(gamma + d);
  const float4 bt = *(const float4*)(beta + d);
  float4 o;
  o.x = (v.x - mu) * inv * g.x + bt.x;
  o.y = (v.y - mu) * inv * g.y + bt.y;
  o.z = (v.z - mu) * inv * g.z + bt.z;
  o.w = (v.w - mu) * inv * g.w + bt.w;
  *(float4*)(out + (size_t)t * Dd + d) = o;
}

// ----------------------------------------------------------------
extern "C" void kernel_launch(void* const* d_in, const int* in_sizes, int n_in,
                              void* d_out, int out_size, void* d_ws, size_t ws_size,
                              hipStream_t stream) {
  (void)in_sizes; (void)n_in; (void)out_size; (void)ws_size;
  const float* x     = (const float*)d_in[0];
  const float* mk    = (const float*)d_in[1];
  const float* W1    = (const float*)d_in[2];
  const float* b1    = (const float*)d_in[3];
  const float* W2    = (const float*)d_in[4];
  const float* b2    = (const float*)d_in[5];
  const float* Wo1   = (const float*)d_in[6];
  const float* bo1   = (const float*)d_in[7];
  const float* Wo2   = (const float*)d_in[8];
  const float* bo2   = (const float*)d_in[9];
  const float* gamma = (const float*)d_in[10];
  const float* beta  = (const float*)d_in[11];
  float* out = (float*)d_out;

  size_t off = 0;
  auto alloc = [&](size_t bytes) -> void* {
    void* p = (char*)d_ws + off;
    off += (bytes + 255) & ~(size_t)255;
    return p;
  };
  unsigned short* xm_h   = (unsigned short*)alloc((size_t)Tt * Dd * 2);
  unsigned short* h1     = (unsigned short*)alloc((size_t)Tt * DMm * 2);
  unsigned short* pre    = (unsigned short*)alloc((size_t)Tt * Dd * 2);
  float*          pscore = (float*)alloc((size_t)Tt * 2 * Pp * 4);
  unsigned short* W1t    = (unsigned short*)alloc((size_t)Pp * Dd * DMm * 2);
  unsigned short* W2t    = (unsigned short*)alloc((size_t)Pp * DMm * Dd * 2);
  unsigned short* Wo1t   = (unsigned short*)alloc((size_t)Dd * DMm * 2);
  int* counts   = (int*)alloc(64 * 4);
  int* nflag    = counts + 16;
  int* flagged  = (int*)alloc(Tt * 4);
  int* tokenlist = (int*)alloc((size_t)Pp * Tt * 4);

  k_prep<<<Tt + (2 * Pp + 1) * 256, 256, 0, stream>>>(
      x, mk, xm_h, W1, W2, Wo1, W1t, W2t, Wo1t, counts);

  k_obs<<<dim3(Tt / 32, DMm / 128), 256, 0, stream>>>(
      xm_h, Wo1t, bo1, Wo2, pscore);
  k_amax<<<Tt / 256, 256, 0, stream>>>(pscore, bo2, nflag, flagged,
                                       counts, tokenlist);
  k_rescue<<<256, 256, 0, stream>>>(x, mk, Wo1, bo1, Wo2, bo2, nflag, flagged,
                                    counts, tokenlist);

  k_gemm<Dd, DMm, 1, 32><<<dim3(MAXT32, DMm / 128), 256, 0, stream>>>(
      xm_h, W1t, b1, nullptr, h1, counts, tokenlist);
  k_gemm<DMm, Dd, 2, 64><<<dim3(MAXTILES, Dd / 128), 256, 0, stream>>>(
      h1, W2t, b2, x, pre, counts, tokenlist);
  k_ln<<<Tt, 256, 0, stream>>>(pre, out, gamma, beta);
}